// Round 9
// baseline (542.280 us; speedup 1.0000x reference)
//
#include <hip/hip_runtime.h>
#include <stdint.h>

// ContextualAttention on MI355X. Inputs/outputs float32; correlation logits via
// 2-term f16 split MFMA (A=[x_hi|x_lo] K=1152, B=w_hi staged twice), bf16 MFMA
// elsewhere, fp32 fuse/softmax.
//
// Round 9 changes:
//  - deconv tap-reduction fused into epilogue via f32 atomicAdd (tap -> unique
//    (phase,shift)); T buffer + k_dred2 + k_zero2 eliminated; k_cvt (x0.25 -> bf16)
//  - k_build_wn / k_build_x stores LDS-staged -> dword-coalesced
//
// ws layout (bytes), total <= 169,869,312:
//  region A [0, 84934656):
//    phase1: Yt f32 (84,934,656)
//    phase2 (after fuse_sm): Ybf f32 [0, 9834496) | Ybt2 bf16 [9834496, +4917248)
//            | Y1t2 bf16 [14751744, +4917248) | Wp1 [19668992, +73728) | Wp2 [19742720, +73728)
//  region B [84934656, ...):
//    phase1: Wn f16 (10,616,832) + Xb f16 (21,233,664)
//    phase2: Pt2 bf16 [SZ_BUF, +46080000) | Rwa [+46080000, +18874368)

#define SZ_BUF 84934656ull
typedef __attribute__((ext_vector_type(8))) short short8;
typedef __attribute__((ext_vector_type(8))) _Float16 half8;
typedef __attribute__((ext_vector_type(4))) float f32x4;
typedef __attribute__((ext_vector_type(4), aligned(4))) float f32x4u;
typedef __attribute__((ext_vector_type(4))) short s16x4;

#if defined(__has_builtin)
#if __has_builtin(__builtin_amdgcn_global_load_lds)
#define HAVE_GLL 1
#endif
#endif

#ifdef HAVE_GLL
typedef const __attribute__((address_space(1))) void* gp1_t;
typedef __attribute__((address_space(3))) void* lp3_t;
__device__ __forceinline__ void gl_lds16(const void* g, void* l){
  __builtin_amdgcn_global_load_lds((gp1_t)g, (lp3_t)l, 16, 0, 0);
}
#else
__device__ __forceinline__ void gl_lds16(const void* g, void* l){
  *(short8*)l = *(const short8*)g;
}
#endif

__device__ __forceinline__ float b2f(uint16_t u){
  union { uint32_t i; float f; } v; v.i = ((uint32_t)u) << 16; return v.f;
}
__device__ __forceinline__ uint16_t f2b(float f){
  uint32_t x = __float_as_uint(f);
  uint32_t r = (x + 0x7FFFu + ((x >> 16) & 1u)) >> 16;
  return (uint16_t)r;
}
__device__ __forceinline__ uint16_t f2h(float f){
  union { _Float16 h; uint16_t u; } v; v.h = (_Float16)f; return v.u;
}
__device__ __forceinline__ float h2f(uint16_t u){
  union { uint16_t u; _Float16 h; } v; v.u = u; return (float)v.h;
}
__device__ __forceinline__ int gfun(int x, int d){
  int t = (x % 48) * 48 + (x / 48) + d;
  if ((unsigned)t >= 2304u) return -1;
  return (t % 48) * 48 + (t / 48);
}

// ---------------- prep kernels (LDS-staged coalesced stores) ----------------

__global__ void k_build_wn(const float* __restrict__ bsrc, uint16_t* __restrict__ wn){
  __shared__ uint16_t lds[576];
  int o = blockIdx.x, item = blockIdx.y, c = threadIdx.x;
  int m = o * 64 + c;
  int c0 = m / 2304, rem = m % 2304, i = rem / 48, j = rem % 48;
  const float* bp = bsrc + ((size_t)item * 64 + c0) * 9216;
  float v[9]; float ss = 0.f;
#pragma unroll
  for (int p = 0; p < 3; p++)
#pragma unroll
    for (int q = 0; q < 3; q++){
      int y = i + p - 1, x = j + q - 1;
      float val = 0.f;
      if ((unsigned)y < 48u && (unsigned)x < 48u) val = bp[y * 192 + x * 2];
      v[p * 3 + q] = val; ss += val * val;
    }
#pragma unroll
  for (int off = 32; off > 0; off >>= 1) ss += __shfl_xor(ss, off, 64);
  float inv = 1.f / fmaxf(sqrtf(ss), 1e-4f);
#pragma unroll
  for (int t = 0; t < 9; t++) lds[c * 9 + t] = f2h(v[t] * inv);
  __syncthreads();
  uint32_t* d32 = (uint32_t*)(wn + ((size_t)item * 2304 + o) * 576);
  const uint32_t* s32 = (const uint32_t*)lds;
#pragma unroll
  for (int k = 0; k < 5; k++){
    int idx = k * 64 + c;
    if (idx < 288) d32[idx] = s32[idx];
  }
}

__global__ void k_build_x(const float* __restrict__ fsrc, uint16_t* __restrict__ xb){
  __shared__ uint16_t lds[1152];
  int s = blockIdx.x, item = blockIdx.y, c = threadIdx.x;
  int y = s / 48, x = s % 48;
  const float* fp = fsrc + ((size_t)item * 64 + c) * 9216;
#pragma unroll
  for (int p = 0; p < 3; p++)
#pragma unroll
    for (int q = 0; q < 3; q++){
      int yy = y + p - 1, xx = x + q - 1;
      float val = 0.f;
      if ((unsigned)yy < 48u && (unsigned)xx < 48u) val = fp[yy * 192 + xx * 2];
      uint16_t hi = f2h(val);
      int t = p * 3 + q;
      lds[c * 9 + t] = hi;
      lds[576 + c * 9 + t] = f2h(val - h2f(hi));
    }
  __syncthreads();
  uint32_t* d32 = (uint32_t*)(xb + ((size_t)item * 2304 + s) * 1152);
  const uint32_t* s32 = (const uint32_t*)lds;
#pragma unroll
  for (int k = 0; k < 9; k++){
    int idx = k * 64 + c;
    d32[idx] = s32[idx];
  }
}

// ---------------- correlation GEMM: Yt[s][o] = X @ Wn^T, M=N=2304, K=1152 (f16) ----------------

__launch_bounds__(256)
__global__ void k_gemm_corr(const uint16_t* __restrict__ A, const uint16_t* __restrict__ B,
                            float* __restrict__ Cd){
  __shared__ __align__(16) uint16_t As[128 * 32];
  __shared__ __align__(16) uint16_t Bs[128 * 32];
  int item = blockIdx.z;
  int n0 = blockIdx.x * 128, m0 = blockIdx.y * 128;
  const uint16_t* Ap = A + (size_t)item * 2304 * 1152;
  const uint16_t* Bp = B + (size_t)item * 2304 * 576;
  int tid = threadIdx.x;
  int wave = tid >> 6, lane = tid & 63, lm = lane & 15, lg = lane >> 4;
  int wy = wave >> 1, wx = wave & 1;
  int swl = (lg ^ ((lm >> 2) & 3)) * 8;
  f32x4 acc[4][4] = {};
  for (int kt = 0; kt < 36; kt++){
    int kb = kt * 32;
    int bkb = (kt < 18) ? kb : kb - 576;
#pragma unroll
    for (int c = tid; c < 1024; c += 256){
      int cc = c & 511;
      int row = cc >> 2, j = cc & 3;
      int sw = (j ^ ((row >> 2) & 3)) * 8;
      if (c < 512)
        gl_lds16(&Ap[(size_t)(m0 + row) * 1152 + kb + sw], &As[cc * 8]);
      else
        gl_lds16(&Bp[(size_t)(n0 + row) * 576 + bkb + sw], &Bs[cc * 8]);
    }
    __syncthreads();
    half8 af[4], bf[4];
#pragma unroll
    for (int i = 0; i < 4; i++){
      af[i] = *(const half8*)&As[(wy * 64 + i * 16 + lm) * 32 + swl];
      bf[i] = *(const half8*)&Bs[(wx * 64 + i * 16 + lm) * 32 + swl];
    }
#pragma unroll
    for (int i = 0; i < 4; i++)
#pragma unroll
      for (int j = 0; j < 4; j++)
        acc[i][j] = __builtin_amdgcn_mfma_f32_16x16x32_f16(af[i], bf[j], acc[i][j], 0, 0, 0);
    __syncthreads();
  }
  float* Cp = Cd + (size_t)item * 2304 * 2304;
#pragma unroll
  for (int i = 0; i < 4; i++){
    int rb = m0 + wy * 64 + i * 16 + lg * 4;
#pragma unroll
    for (int j = 0; j < 4; j++){
      int cc = n0 + wx * 64 + j * 16 + lm;
#pragma unroll
      for (int r = 0; r < 4; r++)
        Cp[(size_t)(rb + r) * 2304 + cc] = acc[i][j][r];
    }
  }
}

// ---------------- merged fuse + softmax (vectorized) ----------------

__global__ void k_fuse_sm(const float* __restrict__ Yt, uint16_t* __restrict__ pt2){
  __shared__ float red[4];
  int s = blockIdx.x, item = blockIdx.y, t = threadIdx.x;
  const float* yp = Yt + (size_t)item * 2304 * 2304;
  int rs[3]; rs[0] = gfun(s, -1); rs[1] = s; rs[2] = gfun(s, 1);
  int nact = (t < 64) ? 3 : 2;
  f32x4u v[3];
  for (int u = 0; u < 3; u++){
    f32x4u acc = {0.f, 0.f, 0.f, 0.f};
    if (u < nact){
      int g = t + u * 256;
      int o0 = 4 * g, orr = o0 / 48, oc0 = o0 % 48;
#pragma unroll
      for (int dd = 0; dd < 3; dd++){
        int a0 = rs[dd];
        if (a0 < 0) continue;
        int d = dd - 1;
        int base; int vm = 0xF;
        if (d == 0) base = o0;
        else {
          int tor = orr + d;
          if ((unsigned)tor < 48u) base = tor * 48 + oc0;
          else if (tor < 0){ base = 2255 + oc0; if (oc0 == 0) vm = 0xE; }
          else { base = oc0 + 1; if (oc0 == 44) vm = 0x7; }
        }
#pragma unroll
        for (int e = -1; e <= 1; e++){
          int a = a0 + e;
          if ((unsigned)a >= 2304u) continue;
          int cb = base + e;
          const float* rowp = yp + (size_t)a * 2304;
          if (vm == 0xF && cb >= 0 && cb + 3 < 2304){
            acc += *(const f32x4u*)&rowp[cb];
          } else {
#pragma unroll
            for (int i = 0; i < 4; i++)
              if ((vm >> i) & 1){
                int c2 = cb + i;
                if ((unsigned)c2 < 2304u) acc[i] += rowp[c2];
              }
          }
        }
      }
    }
    v[u] = acc;
  }
  float mx = -3.4e38f;
  for (int u = 0; u < nact; u++)
#pragma unroll
    for (int i = 0; i < 4; i++) mx = fmaxf(mx, v[u][i]);
#pragma unroll
  for (int off = 32; off > 0; off >>= 1) mx = fmaxf(mx, __shfl_xor(mx, off, 64));
  if ((t & 63) == 0) red[t >> 6] = mx;
  __syncthreads();
  mx = fmaxf(fmaxf(red[0], red[1]), fmaxf(red[2], red[3]));
  float sum = 0.f;
  for (int u = 0; u < nact; u++)
#pragma unroll
    for (int i = 0; i < 4; i++){ v[u][i] = __expf(10.f * (v[u][i] - mx)); sum += v[u][i]; }
#pragma unroll
  for (int off = 32; off > 0; off >>= 1) sum += __shfl_xor(sum, off, 64);
  __syncthreads();
  if ((t & 63) == 0) red[t >> 6] = sum;
  __syncthreads();
  float inv = 1.f / (red[0] + red[1] + red[2] + red[3]);
  uint16_t* pr = pt2 + ((size_t)item * 2500 + (size_t)(s / 48 + 1) * 50 + (s % 48) + 1) * 2304;
  for (int u = 0; u < nact; u++){
    s16x4 w;
#pragma unroll
    for (int i = 0; i < 4; i++) w[i] = (short)f2b(v[u][i] * inv);
    *(s16x4*)&pr[4 * (t + u * 256)] = w;
  }
}

__global__ void k_zero_pad(uint16_t* __restrict__ pt2){
  int p = blockIdx.x, item = blockIdx.y, t = threadIdx.x;
  int sy, sx;
  if (p < 50){ sy = 0; sx = p; }
  else if (p < 100){ sy = 49; sx = p - 50; }
  else if (p < 148){ sy = p - 99; sx = 0; }
  else { sy = p - 147; sx = 49; }
  uint16_t* pr = pt2 + ((size_t)item * 2500 + sy * 50 + sx) * 2304;
  short8 z = {};
  for (int c = t; c < 288; c += 256) *(short8*)&pr[c * 8] = z;
}

// zero Ybf + Ybt2 + Y1t2 region: [0, 19668992) bytes = 1229312 x 16B
__global__ void k_prep_zero(f32x4* __restrict__ p){
  size_t i = (size_t)blockIdx.x * 256 + threadIdx.x;
  if (i < 1229312u){ f32x4 z = {}; p[i] = z; }
}

// ---------------- raw 4x4 patch bank, layout [item][tap16][co][l] ----------------

__global__ void k_build_rwa(const float* __restrict__ bsrc, uint16_t* __restrict__ rwa){
  __shared__ uint16_t tile[64][66];
  int item = blockIdx.y, l0 = blockIdx.x * 64;
  const float* bp = bsrc + (size_t)item * 64 * 9216;
  int wave = threadIdx.x >> 6, lane = threadIdx.x & 63;
  for (int tap = 0; tap < 16; tap++){
    int py = tap >> 2, qx = tap & 3;
#pragma unroll
    for (int step = 0; step < 16; step++){
      int lsub = wave * 16 + step;
      int l = l0 + lsub, co = lane;
      int m = l * 64 + co;
      int c0 = m / 2304, rem = m % 2304, i = rem / 48, jj = rem % 48;
      int Y = 2 * i + py - 1, X = 2 * jj + qx - 1;
      float val = 0.f;
      if ((unsigned)Y < 96u && (unsigned)X < 96u) val = bp[(size_t)c0 * 9216 + Y * 96 + X];
      tile[lsub][co] = f2b(val);
    }
    __syncthreads();
#pragma unroll
    for (int step = 0; step < 16; step++){
      int co = wave * 16 + step;
      rwa[(((size_t)item * 16 + tap) * 64 + co) * 2304 + l0 + lane] = tile[lane][co];
    }
    __syncthreads();
  }
}

// ---------------- deconv GEMM + fused tap-reduction epilogue ----------------
// M=1024 (tap*64+co), N=2560 (padded 50x50 sp), K=2304. Each tap maps to a unique
// (phase fy,fx; shift ay,ax): fy=1-(py&1), ay=1-(py>>1). Epilogue: atomicAdd into
// f32 Ybf[98][98][64] at pixel (2my+fy+1, 2mx+fx+1), my=spy-ay-fy, mx=spx-ax-fx.

__launch_bounds__(256)
__global__ void k_deconv3(const uint16_t* __restrict__ rwa, const uint16_t* __restrict__ pt2,
                          float* __restrict__ ybf){
  __shared__ __align__(16) uint16_t As[128 * 32];
  __shared__ __align__(16) uint16_t Bs[128 * 32];
  int item = blockIdx.z;
  int n0 = blockIdx.x * 128, m0 = blockIdx.y * 128;
  const uint16_t* Ap = rwa + (size_t)item * 1024 * 2304;
  const uint16_t* Bp = pt2 + (size_t)item * 2500 * 2304;   // rows >= 2500 read garbage; dropped below
  int tid = threadIdx.x;
  int wave = tid >> 6, lane = tid & 63, lm = lane & 15, lg = lane >> 4;
  int wy = wave >> 1, wx = wave & 1;
  int swl = (lg ^ ((lm >> 2) & 3)) * 8;
  f32x4 acc[4][4] = {};
  for (int kt = 0; kt < 72; kt++){
    int kb = kt * 32;
#pragma unroll
    for (int c = tid; c < 1024; c += 256){
      int cc = c & 511;
      int row = cc >> 2, j = cc & 3;
      int sw = (j ^ ((row >> 2) & 3)) * 8;
      if (c < 512)
        gl_lds16(&Ap[(size_t)(m0 + row) * 2304 + kb + sw], &As[cc * 8]);
      else
        gl_lds16(&Bp[(size_t)(n0 + row) * 2304 + kb + sw], &Bs[cc * 8]);
    }
    __syncthreads();
    short8 af[4], bf[4];
#pragma unroll
    for (int i = 0; i < 4; i++){
      af[i] = *(const short8*)&As[(wy * 64 + i * 16 + lm) * 32 + swl];
      bf[i] = *(const short8*)&Bs[(wx * 64 + i * 16 + lm) * 32 + swl];
    }
#pragma unroll
    for (int i = 0; i < 4; i++)
#pragma unroll
      for (int j = 0; j < 4; j++)
        acc[i][j] = __builtin_amdgcn_mfma_f32_16x16x32_bf16(af[i], bf[j], acc[i][j], 0, 0, 0);
    __syncthreads();
  }
  float* Yp = ybf + (size_t)item * 98 * 98 * 64;
  int spy[4], spx[4];
#pragma unroll
  for (int j = 0; j < 4; j++){
    int sp = n0 + wx * 64 + j * 16 + lm;
    spy[j] = sp / 50; spx[j] = sp % 50;
  }
#pragma unroll
  for (int i = 0; i < 4; i++){
    int m = m0 + wy * 64 + i * 16 + lg * 4;
    int tap = m >> 6, co = m & 63;
    int py = tap >> 2, qx = tap & 3;
    int fy = 1 - (py & 1), ay = 1 - (py >> 1);
    int fx = 1 - (qx & 1), ax = 1 - (qx >> 1);
    int dy = ay + fy, dx = ax + fx;
#pragma unroll
    for (int j = 0; j < 4; j++){
      int my = spy[j] - dy, mx = spx[j] - dx;
      if ((unsigned)my < 48u && (unsigned)mx < 48u){
        int Y = 2 * my + fy + 1, X = 2 * mx + fx + 1;
        float* base = Yp + ((size_t)(Y * 98 + X)) * 64 + co;
#pragma unroll
        for (int r = 0; r < 4; r++) atomicAdd(base + r, acc[i][j][r]);
      }
    }
  }
}

// Ybf f32 -> Ybt2 bf16 (x0.25), 2,458,624 elements, vectorized x4
__global__ void k_cvt(const float* __restrict__ src, uint16_t* __restrict__ dst){
  size_t i = ((size_t)blockIdx.x * 256 + threadIdx.x) * 4;
  if (i < 2458624u){
    f32x4 v = *(const f32x4*)&src[i];
    s16x4 w;
#pragma unroll
    for (int r = 0; r < 4; r++) w[r] = (short)f2b(v[r] * 0.25f);
    *(s16x4*)&dst[i] = w;
  }
}

// ---------------- final 3x3 convs (direct from padded layout) ----------------

__global__ void k_pack_w(const float* __restrict__ w1, const float* __restrict__ w2,
                         uint16_t* __restrict__ p1, uint16_t* __restrict__ p2){
  int i = blockIdx.x * 256 + threadIdx.x;
  if (i < 36864){
    int co = i / 576, rem = i % 576, ci = rem / 9, t = rem % 9;
    int di = co * 576 + t * 64 + ci;
    p1[di] = f2b(w1[i]); p2[di] = f2b(w2[i]);
  }
}

__launch_bounds__(256)
__global__ void k_conv_gemm2(const uint16_t* __restrict__ Wp, const uint16_t* __restrict__ Src,
                             const float* __restrict__ bias,
                             uint16_t* __restrict__ dst16, float* __restrict__ dst32){
  __shared__ __align__(16) uint16_t As[64 * 32];
  __shared__ __align__(16) uint16_t Bs[128 * 32];
  int n0 = blockIdx.x * 128, item = blockIdx.z;
  int tid = threadIdx.x, wave = tid >> 6, lane = tid & 63, lm = lane & 15, lg = lane >> 4;
  int swl = (lg ^ ((lm >> 2) & 3)) * 8;
  const uint16_t* Bp = Src + (size_t)item * 98 * 98 * 64;
  f32x4 acc[4][2] = {};
  for (int kt = 0; kt < 18; kt++){
    int t = kt >> 1, cb = (kt & 1) * 32;
    int py = t / 3, qx = t % 3;
#pragma unroll
    for (int c = tid; c < 768; c += 256){
      if (c < 256){
        int row = c >> 2, j = c & 3;
        int sw = (j ^ ((row >> 2) & 3)) * 8;
        gl_lds16(&Wp[(size_t)row * 576 + kt * 32 + sw], &As[c * 8]);
      } else {
        int cc = c - 256; int row = cc >> 2, j = cc & 3;
        int sw = (j ^ ((row >> 2) & 3)) * 8;
        int n = n0 + row; int y = n / 96, x = n % 96;
        gl_lds16(&Bp[((size_t)(y + py) * 98 + (x + qx)) * 64 + cb + sw], &Bs[cc * 8]);
      }
    }
    __syncthreads();
    short8 af[4], bf[2];
#pragma unroll
    for (int i = 0; i < 4; i++) af[i] = *(const short8*)&As[(i * 16 + lm) * 32 + swl];
#pragma unroll
    for (int j = 0; j < 2; j++) bf[j] = *(const short8*)&Bs[(wave * 32 + j * 16 + lm) * 32 + swl];
#pragma unroll
    for (int i = 0; i < 4; i++)
#pragma unroll
      for (int j = 0; j < 2; j++)
        acc[i][j] = __builtin_amdgcn_mfma_f32_16x16x32_bf16(af[i], bf[j], acc[i][j], 0, 0, 0);
    __syncthreads();
  }
  if (dst32){
#pragma unroll
    for (int i = 0; i < 4; i++)
#pragma unroll
      for (int j = 0; j < 2; j++){
        int n = n0 + wave * 32 + j * 16 + lm;
#pragma unroll
        for (int r = 0; r < 4; r++){
          int co = i * 16 + lg * 4 + r;
          dst32[((size_t)item * 64 + co) * 9216 + n] = acc[i][j][r] + bias[co];
        }
      }
  } else {
    uint16_t* dp = dst16 + (size_t)item * 98 * 98 * 64;
#pragma unroll
    for (int i = 0; i < 4; i++)
#pragma unroll
      for (int j = 0; j < 2; j++){
        int n = n0 + wave * 32 + j * 16 + lm;
        int y = n / 96, x = n % 96;
        int co0 = i * 16 + lg * 4;
        s16x4 w;
#pragma unroll
        for (int r = 0; r < 4; r++) w[r] = (short)f2b(acc[i][j][r] + bias[co0 + r]);
        *(s16x4*)&dp[((size_t)(y + 1) * 98 + (x + 1)) * 64 + co0] = w;
      }
  }
}

// ---------------- launch ----------------

extern "C" void kernel_launch(void* const* d_in, const int* in_sizes, int n_in,
                              void* d_out, int out_size, void* d_ws, size_t ws_size,
                              hipStream_t stream){
  const float* f  = (const float*)d_in[0];
  const float* b  = (const float*)d_in[1];
  const float* w1 = (const float*)d_in[2];
  const float* b1 = (const float*)d_in[3];
  const float* w2 = (const float*)d_in[4];
  const float* b2 = (const float*)d_in[5];
  char* ws = (char*)d_ws;
  // region A
  float*    Yt   = (float*)ws;                          // 84,934,656 B (phase1)
  float*    Ybf  = (float*)ws;                          //  9,834,496 B (over dead Yt)
  uint16_t* Ybt2 = (uint16_t*)(ws + 9834496ull);        //  4,917,248 B
  uint16_t* Y1t2 = (uint16_t*)(ws + 14751744ull);       //  4,917,248 B
  uint16_t* Wp1  = (uint16_t*)(ws + 19668992ull);       //     73,728 B
  uint16_t* Wp2  = (uint16_t*)(ws + 19742720ull);       //     73,728 B
  // region B
  uint16_t* Wn   = (uint16_t*)(ws + SZ_BUF);            // 10,616,832 B (f16 w_hi, stride 576)
  uint16_t* Xb   = Wn + (size_t)4 * 2304 * 576;         // 21,233,664 B (f16 [hi|lo], stride 1152)
  uint16_t* Pt2  = (uint16_t*)(ws + SZ_BUF);            // 46,080,000 B (over dead Wn/Xb)
  uint16_t* Rwa  = (uint16_t*)(ws + SZ_BUF + 46080000ull); // 18,874,368 B
  float*    out  = (float*)d_out;

  k_build_wn<<<dim3(2304, 4), 64, 0, stream>>>(b, Wn);
  k_build_x<<<dim3(2304, 4), 64, 0, stream>>>(f, Xb);
  k_gemm_corr<<<dim3(18, 18, 4), 256, 0, stream>>>(Xb, Wn, Yt);   // A=Xb (1152) -> rows=s
  k_zero_pad<<<dim3(196, 4), 256, 0, stream>>>(Pt2);              // Wn/Xb dead now
  k_build_rwa<<<dim3(36, 4), 256, 0, stream>>>(b, Rwa);
  k_fuse_sm<<<dim3(2304, 4), 256, 0, stream>>>(Yt, Pt2);
  k_prep_zero<<<dim3(4803), 256, 0, stream>>>((f32x4*)ws);        // Yt dead now
  k_pack_w<<<dim3(144), 256, 0, stream>>>(w1, w2, Wp1, Wp2);
  k_deconv3<<<dim3(20, 8, 4), 256, 0, stream>>>(Rwa, Pt2, Ybf);
  k_cvt<<<dim3(2401), 256, 0, stream>>>(Ybf, Ybt2);
  k_conv_gemm2<<<dim3(72, 1, 4), 256, 0, stream>>>(Wp1, Ybt2, b1, Y1t2, nullptr);
  k_conv_gemm2<<<dim3(72, 1, 4), 256, 0, stream>>>(Wp2, Y1t2, b2, nullptr, out);
}

// Round 10
// 510.872 us; speedup vs baseline: 1.0615x; 1.0615x over previous
//
#include <hip/hip_runtime.h>
#include <stdint.h>

// ContextualAttention on MI355X. Inputs/outputs float32; correlation logits via
// 2-term f16 split MFMA (A=[x_hi|x_lo] K=1152, B=w_hi staged twice), bf16 MFMA
// elsewhere, fp32 fuse/softmax.
//
// Round 10: revert round-9 atomic deconv (write-amplification regression, 147 MB
// scattered-atomic WRITE) back to round-8 T+dred2; NEW: k_fuse_sm batches 8
// consecutive s per block (3-band row reuse -> L2 hits, FETCH ~160->~80 MB).
//
// ws layout (bytes), total <= 169,869,312:
//  region A [0, 84934656):
//    phase1: Yt f32 (84,934,656)
//    phase2: T bf16 [0, 20971520) | Ybt2 [20971520, +4917248) | Y1t2 [25888768, +4917248)
//            | Wp1 [30806016, +73728) | Wp2 [30879744, +73728)
//  region B [84934656, ...):
//    phase1: Wn f16 (10,616,832) + Xb f16 (21,233,664)
//    phase2: Pt2 bf16 [SZ_BUF, +46080000) | Rwa [+46080000, +18874368)

#define SZ_BUF 84934656ull
typedef __attribute__((ext_vector_type(8))) short short8;
typedef __attribute__((ext_vector_type(8))) _Float16 half8;
typedef __attribute__((ext_vector_type(4))) float f32x4;
typedef __attribute__((ext_vector_type(4), aligned(4))) float f32x4u;
typedef __attribute__((ext_vector_type(4))) short s16x4;

#if defined(__has_builtin)
#if __has_builtin(__builtin_amdgcn_global_load_lds)
#define HAVE_GLL 1
#endif
#endif

#ifdef HAVE_GLL
typedef const __attribute__((address_space(1))) void* gp1_t;
typedef __attribute__((address_space(3))) void* lp3_t;
__device__ __forceinline__ void gl_lds16(const void* g, void* l){
  __builtin_amdgcn_global_load_lds((gp1_t)g, (lp3_t)l, 16, 0, 0);
}
#else
__device__ __forceinline__ void gl_lds16(const void* g, void* l){
  *(short8*)l = *(const short8*)g;
}
#endif

__device__ __forceinline__ float b2f(uint16_t u){
  union { uint32_t i; float f; } v; v.i = ((uint32_t)u) << 16; return v.f;
}
__device__ __forceinline__ uint16_t f2b(float f){
  uint32_t x = __float_as_uint(f);
  uint32_t r = (x + 0x7FFFu + ((x >> 16) & 1u)) >> 16;
  return (uint16_t)r;
}
__device__ __forceinline__ uint16_t f2h(float f){
  union { _Float16 h; uint16_t u; } v; v.h = (_Float16)f; return v.u;
}
__device__ __forceinline__ float h2f(uint16_t u){
  union { uint16_t u; _Float16 h; } v; v.u = u; return (float)v.h;
}
__device__ __forceinline__ int gfun(int x, int d){
  int t = (x % 48) * 48 + (x / 48) + d;
  if ((unsigned)t >= 2304u) return -1;
  return (t % 48) * 48 + (t / 48);
}

// ---------------- prep kernels (LDS-staged coalesced stores) ----------------

__global__ void k_build_wn(const float* __restrict__ bsrc, uint16_t* __restrict__ wn){
  __shared__ uint16_t lds[576];
  int o = blockIdx.x, item = blockIdx.y, c = threadIdx.x;
  int m = o * 64 + c;
  int c0 = m / 2304, rem = m % 2304, i = rem / 48, j = rem % 48;
  const float* bp = bsrc + ((size_t)item * 64 + c0) * 9216;
  float v[9]; float ss = 0.f;
#pragma unroll
  for (int p = 0; p < 3; p++)
#pragma unroll
    for (int q = 0; q < 3; q++){
      int y = i + p - 1, x = j + q - 1;
      float val = 0.f;
      if ((unsigned)y < 48u && (unsigned)x < 48u) val = bp[y * 192 + x * 2];
      v[p * 3 + q] = val; ss += val * val;
    }
#pragma unroll
  for (int off = 32; off > 0; off >>= 1) ss += __shfl_xor(ss, off, 64);
  float inv = 1.f / fmaxf(sqrtf(ss), 1e-4f);
#pragma unroll
  for (int t = 0; t < 9; t++) lds[c * 9 + t] = f2h(v[t] * inv);
  __syncthreads();
  uint32_t* d32 = (uint32_t*)(wn + ((size_t)item * 2304 + o) * 576);
  const uint32_t* s32 = (const uint32_t*)lds;
#pragma unroll
  for (int k = 0; k < 5; k++){
    int idx = k * 64 + c;
    if (idx < 288) d32[idx] = s32[idx];
  }
}

__global__ void k_build_x(const float* __restrict__ fsrc, uint16_t* __restrict__ xb){
  __shared__ uint16_t lds[1152];
  int s = blockIdx.x, item = blockIdx.y, c = threadIdx.x;
  int y = s / 48, x = s % 48;
  const float* fp = fsrc + ((size_t)item * 64 + c) * 9216;
#pragma unroll
  for (int p = 0; p < 3; p++)
#pragma unroll
    for (int q = 0; q < 3; q++){
      int yy = y + p - 1, xx = x + q - 1;
      float val = 0.f;
      if ((unsigned)yy < 48u && (unsigned)xx < 48u) val = fp[yy * 192 + xx * 2];
      uint16_t hi = f2h(val);
      int t = p * 3 + q;
      lds[c * 9 + t] = hi;
      lds[576 + c * 9 + t] = f2h(val - h2f(hi));
    }
  __syncthreads();
  uint32_t* d32 = (uint32_t*)(xb + ((size_t)item * 2304 + s) * 1152);
  const uint32_t* s32 = (const uint32_t*)lds;
#pragma unroll
  for (int k = 0; k < 9; k++){
    int idx = k * 64 + c;
    d32[idx] = s32[idx];
  }
}

// ---------------- correlation GEMM: Yt[s][o] = X @ Wn^T, M=N=2304, K=1152 (f16) ----------------

__launch_bounds__(256)
__global__ void k_gemm_corr(const uint16_t* __restrict__ A, const uint16_t* __restrict__ B,
                            float* __restrict__ Cd){
  __shared__ __align__(16) uint16_t As[128 * 32];
  __shared__ __align__(16) uint16_t Bs[128 * 32];
  int item = blockIdx.z;
  int n0 = blockIdx.x * 128, m0 = blockIdx.y * 128;
  const uint16_t* Ap = A + (size_t)item * 2304 * 1152;
  const uint16_t* Bp = B + (size_t)item * 2304 * 576;
  int tid = threadIdx.x;
  int wave = tid >> 6, lane = tid & 63, lm = lane & 15, lg = lane >> 4;
  int wy = wave >> 1, wx = wave & 1;
  int swl = (lg ^ ((lm >> 2) & 3)) * 8;
  f32x4 acc[4][4] = {};
  for (int kt = 0; kt < 36; kt++){
    int kb = kt * 32;
    int bkb = (kt < 18) ? kb : kb - 576;
#pragma unroll
    for (int c = tid; c < 1024; c += 256){
      int cc = c & 511;
      int row = cc >> 2, j = cc & 3;
      int sw = (j ^ ((row >> 2) & 3)) * 8;
      if (c < 512)
        gl_lds16(&Ap[(size_t)(m0 + row) * 1152 + kb + sw], &As[cc * 8]);
      else
        gl_lds16(&Bp[(size_t)(n0 + row) * 576 + bkb + sw], &Bs[cc * 8]);
    }
    __syncthreads();
    half8 af[4], bf[4];
#pragma unroll
    for (int i = 0; i < 4; i++){
      af[i] = *(const half8*)&As[(wy * 64 + i * 16 + lm) * 32 + swl];
      bf[i] = *(const half8*)&Bs[(wx * 64 + i * 16 + lm) * 32 + swl];
    }
#pragma unroll
    for (int i = 0; i < 4; i++)
#pragma unroll
      for (int j = 0; j < 4; j++)
        acc[i][j] = __builtin_amdgcn_mfma_f32_16x16x32_f16(af[i], bf[j], acc[i][j], 0, 0, 0);
    __syncthreads();
  }
  float* Cp = Cd + (size_t)item * 2304 * 2304;
#pragma unroll
  for (int i = 0; i < 4; i++){
    int rb = m0 + wy * 64 + i * 16 + lg * 4;
#pragma unroll
    for (int j = 0; j < 4; j++){
      int cc = n0 + wx * 64 + j * 16 + lm;
#pragma unroll
      for (int r = 0; r < 4; r++)
        Cp[(size_t)(rb + r) * 2304 + cc] = acc[i][j][r];
    }
  }
}

// ---------------- merged fuse + softmax (vectorized, 8 s per block for L2 reuse) ----------------

__global__ void k_fuse_sm(const float* __restrict__ Yt, uint16_t* __restrict__ pt2){
  __shared__ float red[4];
  int item = blockIdx.y, t = threadIdx.x;
  const float* yp = Yt + (size_t)item * 2304 * 2304;
  int nact = (t < 64) ? 3 : 2;
  for (int si = 0; si < 8; si++){
    int s = blockIdx.x * 8 + si;
    __syncthreads();   // protect red[] reuse across iterations
    int rs[3]; rs[0] = gfun(s, -1); rs[1] = s; rs[2] = gfun(s, 1);
    f32x4u v[3];
    for (int u = 0; u < 3; u++){
      f32x4u acc = {0.f, 0.f, 0.f, 0.f};
      if (u < nact){
        int g = t + u * 256;
        int o0 = 4 * g, orr = o0 / 48, oc0 = o0 % 48;
#pragma unroll
        for (int dd = 0; dd < 3; dd++){
          int a0 = rs[dd];
          if (a0 < 0) continue;
          int d = dd - 1;
          int base; int vm = 0xF;
          if (d == 0) base = o0;
          else {
            int tor = orr + d;
            if ((unsigned)tor < 48u) base = tor * 48 + oc0;
            else if (tor < 0){ base = 2255 + oc0; if (oc0 == 0) vm = 0xE; }
            else { base = oc0 + 1; if (oc0 == 44) vm = 0x7; }
          }
#pragma unroll
          for (int e = -1; e <= 1; e++){
            int a = a0 + e;
            if ((unsigned)a >= 2304u) continue;
            int cb = base + e;
            const float* rowp = yp + (size_t)a * 2304;
            if (vm == 0xF && cb >= 0 && cb + 3 < 2304){
              acc += *(const f32x4u*)&rowp[cb];
            } else {
#pragma unroll
              for (int i = 0; i < 4; i++)
                if ((vm >> i) & 1){
                  int c2 = cb + i;
                  if ((unsigned)c2 < 2304u) acc[i] += rowp[c2];
                }
            }
          }
        }
      }
      v[u] = acc;
    }
    float mx = -3.4e38f;
    for (int u = 0; u < nact; u++)
#pragma unroll
      for (int i = 0; i < 4; i++) mx = fmaxf(mx, v[u][i]);
#pragma unroll
    for (int off = 32; off > 0; off >>= 1) mx = fmaxf(mx, __shfl_xor(mx, off, 64));
    if ((t & 63) == 0) red[t >> 6] = mx;
    __syncthreads();
    mx = fmaxf(fmaxf(red[0], red[1]), fmaxf(red[2], red[3]));
    float sum = 0.f;
    for (int u = 0; u < nact; u++)
#pragma unroll
      for (int i = 0; i < 4; i++){ v[u][i] = __expf(10.f * (v[u][i] - mx)); sum += v[u][i]; }
#pragma unroll
    for (int off = 32; off > 0; off >>= 1) sum += __shfl_xor(sum, off, 64);
    __syncthreads();
    if ((t & 63) == 0) red[t >> 6] = sum;
    __syncthreads();
    float inv = 1.f / (red[0] + red[1] + red[2] + red[3]);
    uint16_t* pr = pt2 + ((size_t)item * 2500 + (size_t)(s / 48 + 1) * 50 + (s % 48) + 1) * 2304;
    for (int u = 0; u < nact; u++){
      s16x4 w;
#pragma unroll
      for (int i = 0; i < 4; i++) w[i] = (short)f2b(v[u][i] * inv);
      *(s16x4*)&pr[4 * (t + u * 256)] = w;
    }
  }
}

__global__ void k_zero_pad(uint16_t* __restrict__ pt2){
  int p = blockIdx.x, item = blockIdx.y, t = threadIdx.x;
  int sy, sx;
  if (p < 50){ sy = 0; sx = p; }
  else if (p < 100){ sy = 49; sx = p - 50; }
  else if (p < 148){ sy = p - 99; sx = 0; }
  else { sy = p - 147; sx = 49; }
  uint16_t* pr = pt2 + ((size_t)item * 2500 + sy * 50 + sx) * 2304;
  short8 z = {};
  for (int c = t; c < 288; c += 256) *(short8*)&pr[c * 8] = z;
}

// ---------------- raw 4x4 patch bank, layout [item][tap16][co][l] ----------------

__global__ void k_build_rwa(const float* __restrict__ bsrc, uint16_t* __restrict__ rwa){
  __shared__ uint16_t tile[64][66];
  int item = blockIdx.y, l0 = blockIdx.x * 64;
  const float* bp = bsrc + (size_t)item * 64 * 9216;
  int wave = threadIdx.x >> 6, lane = threadIdx.x & 63;
  for (int tap = 0; tap < 16; tap++){
    int py = tap >> 2, qx = tap & 3;
#pragma unroll
    for (int step = 0; step < 16; step++){
      int lsub = wave * 16 + step;
      int l = l0 + lsub, co = lane;
      int m = l * 64 + co;
      int c0 = m / 2304, rem = m % 2304, i = rem / 48, jj = rem % 48;
      int Y = 2 * i + py - 1, X = 2 * jj + qx - 1;
      float val = 0.f;
      if ((unsigned)Y < 96u && (unsigned)X < 96u) val = bp[(size_t)c0 * 9216 + Y * 96 + X];
      tile[lsub][co] = f2b(val);
    }
    __syncthreads();
#pragma unroll
    for (int step = 0; step < 16; step++){
      int co = wave * 16 + step;
      rwa[(((size_t)item * 16 + tap) * 64 + co) * 2304 + l0 + lane] = tile[lane][co];
    }
    __syncthreads();
  }
}

// ---------------- deconv GEMM: T[m=tap*64+co][sp] = Rwa . Pt2^T, M=1024,N=2560,K=2304 ----------------

__launch_bounds__(256)
__global__ void k_deconv2(const uint16_t* __restrict__ rwa, const uint16_t* __restrict__ pt2,
                          uint16_t* __restrict__ T){
  __shared__ __align__(16) uint16_t As[128 * 32];
  __shared__ __align__(16) uint16_t Bs[128 * 32];
  int item = blockIdx.z;
  int n0 = blockIdx.x * 128, m0 = blockIdx.y * 128;
  const uint16_t* Ap = rwa + (size_t)item * 1024 * 2304;
  const uint16_t* Bp = pt2 + (size_t)item * 2500 * 2304;   // rows up to 2559 read garbage; discarded
  int tid = threadIdx.x;
  int wave = tid >> 6, lane = tid & 63, lm = lane & 15, lg = lane >> 4;
  int wy = wave >> 1, wx = wave & 1;
  int swl = (lg ^ ((lm >> 2) & 3)) * 8;
  f32x4 acc[4][4] = {};
  for (int kt = 0; kt < 72; kt++){
    int kb = kt * 32;
#pragma unroll
    for (int c = tid; c < 1024; c += 256){
      int cc = c & 511;
      int row = cc >> 2, j = cc & 3;
      int sw = (j ^ ((row >> 2) & 3)) * 8;
      if (c < 512)
        gl_lds16(&Ap[(size_t)(m0 + row) * 2304 + kb + sw], &As[cc * 8]);
      else
        gl_lds16(&Bp[(size_t)(n0 + row) * 2304 + kb + sw], &Bs[cc * 8]);
    }
    __syncthreads();
    short8 af[4], bf[4];
#pragma unroll
    for (int i = 0; i < 4; i++){
      af[i] = *(const short8*)&As[(wy * 64 + i * 16 + lm) * 32 + swl];
      bf[i] = *(const short8*)&Bs[(wx * 64 + i * 16 + lm) * 32 + swl];
    }
#pragma unroll
    for (int i = 0; i < 4; i++)
#pragma unroll
      for (int j = 0; j < 4; j++)
        acc[i][j] = __builtin_amdgcn_mfma_f32_16x16x32_bf16(af[i], bf[j], acc[i][j], 0, 0, 0);
    __syncthreads();
  }
  uint16_t* Tp = T + (size_t)item * 1024 * 2560;
#pragma unroll
  for (int i = 0; i < 4; i++){
    int rb = m0 + wy * 64 + i * 16 + lg * 4;
#pragma unroll
    for (int j = 0; j < 4; j++){
      int cc = n0 + wx * 64 + j * 16 + lm;
#pragma unroll
      for (int r = 0; r < 4; r++)
        Tp[(size_t)(rb + r) * 2560 + cc] = f2b(acc[i][j][r]);
    }
  }
}

// gather 4 taps per output pixel -> padded Ybt2[98][98][64] interior
__global__ void k_dred2(const uint16_t* __restrict__ T, uint16_t* __restrict__ ybt2){
  int my = blockIdx.x, phase = blockIdx.y, item = blockIdx.z;
  int co = threadIdx.x;
  int fy = phase >> 1, fx = phase & 1;
  const uint16_t* Tp = T + (size_t)item * 1024 * 2560;
  uint16_t* op = ybt2 + (size_t)item * 98 * 98 * 64;
  for (int mx = 0; mx < 48; mx++){
    float acc = 0.f;
#pragma unroll
    for (int ay = 0; ay < 2; ay++)
#pragma unroll
      for (int ax = 0; ax < 2; ax++){
        int tap = (3 - fy - 2 * ay) * 4 + (3 - fx - 2 * ax);
        int sp = (my + ay + fy) * 50 + (mx + ax + fx);
        acc += b2f(Tp[(size_t)(tap * 64 + co) * 2560 + sp]);
      }
    int Y = 2 * my + fy + 1, X = 2 * mx + fx + 1;
    op[((size_t)Y * 98 + X) * 64 + co] = f2b(acc * 0.25f);
  }
}

__global__ void k_zero2(uint16_t* __restrict__ p){
  size_t i = ((size_t)blockIdx.x * 256 + threadIdx.x) * 8;
  short8 z = {};
  *(short8*)&p[i] = z;
}

// ---------------- final 3x3 convs (direct from padded layout) ----------------

__global__ void k_pack_w(const float* __restrict__ w1, const float* __restrict__ w2,
                         uint16_t* __restrict__ p1, uint16_t* __restrict__ p2){
  int i = blockIdx.x * 256 + threadIdx.x;
  if (i < 36864){
    int co = i / 576, rem = i % 576, ci = rem / 9, t = rem % 9;
    int di = co * 576 + t * 64 + ci;
    p1[di] = f2b(w1[i]); p2[di] = f2b(w2[i]);
  }
}

__launch_bounds__(256)
__global__ void k_conv_gemm2(const uint16_t* __restrict__ Wp, const uint16_t* __restrict__ Src,
                             const float* __restrict__ bias,
                             uint16_t* __restrict__ dst16, float* __restrict__ dst32){
  __shared__ __align__(16) uint16_t As[64 * 32];
  __shared__ __align__(16) uint16_t Bs[128 * 32];
  int n0 = blockIdx.x * 128, item = blockIdx.z;
  int tid = threadIdx.x, wave = tid >> 6, lane = tid & 63, lm = lane & 15, lg = lane >> 4;
  int swl = (lg ^ ((lm >> 2) & 3)) * 8;
  const uint16_t* Bp = Src + (size_t)item * 98 * 98 * 64;
  f32x4 acc[4][2] = {};
  for (int kt = 0; kt < 18; kt++){
    int t = kt >> 1, cb = (kt & 1) * 32;
    int py = t / 3, qx = t % 3;
#pragma unroll
    for (int c = tid; c < 768; c += 256){
      if (c < 256){
        int row = c >> 2, j = c & 3;
        int sw = (j ^ ((row >> 2) & 3)) * 8;
        gl_lds16(&Wp[(size_t)row * 576 + kt * 32 + sw], &As[c * 8]);
      } else {
        int cc = c - 256; int row = cc >> 2, j = cc & 3;
        int sw = (j ^ ((row >> 2) & 3)) * 8;
        int n = n0 + row; int y = n / 96, x = n % 96;
        gl_lds16(&Bp[((size_t)(y + py) * 98 + (x + qx)) * 64 + cb + sw], &Bs[cc * 8]);
      }
    }
    __syncthreads();
    short8 af[4], bf[2];
#pragma unroll
    for (int i = 0; i < 4; i++) af[i] = *(const short8*)&As[(i * 16 + lm) * 32 + swl];
#pragma unroll
    for (int j = 0; j < 2; j++) bf[j] = *(const short8*)&Bs[(wave * 32 + j * 16 + lm) * 32 + swl];
#pragma unroll
    for (int i = 0; i < 4; i++)
#pragma unroll
      for (int j = 0; j < 2; j++)
        acc[i][j] = __builtin_amdgcn_mfma_f32_16x16x32_bf16(af[i], bf[j], acc[i][j], 0, 0, 0);
    __syncthreads();
  }
  if (dst32){
#pragma unroll
    for (int i = 0; i < 4; i++)
#pragma unroll
      for (int j = 0; j < 2; j++){
        int n = n0 + wave * 32 + j * 16 + lm;
#pragma unroll
        for (int r = 0; r < 4; r++){
          int co = i * 16 + lg * 4 + r;
          dst32[((size_t)item * 64 + co) * 9216 + n] = acc[i][j][r] + bias[co];
        }
      }
  } else {
    uint16_t* dp = dst16 + (size_t)item * 98 * 98 * 64;
#pragma unroll
    for (int i = 0; i < 4; i++)
#pragma unroll
      for (int j = 0; j < 2; j++){
        int n = n0 + wave * 32 + j * 16 + lm;
        int y = n / 96, x = n % 96;
        int co0 = i * 16 + lg * 4;
        s16x4 w;
#pragma unroll
        for (int r = 0; r < 4; r++) w[r] = (short)f2b(acc[i][j][r] + bias[co0 + r]);
        *(s16x4*)&dp[((size_t)(y + 1) * 98 + (x + 1)) * 64 + co0] = w;
      }
  }
}

// ---------------- launch ----------------

extern "C" void kernel_launch(void* const* d_in, const int* in_sizes, int n_in,
                              void* d_out, int out_size, void* d_ws, size_t ws_size,
                              hipStream_t stream){
  const float* f  = (const float*)d_in[0];
  const float* b  = (const float*)d_in[1];
  const float* w1 = (const float*)d_in[2];
  const float* b1 = (const float*)d_in[3];
  const float* w2 = (const float*)d_in[4];
  const float* b2 = (const float*)d_in[5];
  char* ws = (char*)d_ws;
  // region A
  float*    Yt   = (float*)ws;                          // 84,934,656 B (phase1)
  uint16_t* T    = (uint16_t*)ws;                       // 20,971,520 B (over dead Yt)
  uint16_t* Ybt2 = (uint16_t*)(ws + 20971520ull);       //  4,917,248 B
  uint16_t* Y1t2 = (uint16_t*)(ws + 25888768ull);       //  4,917,248 B
  uint16_t* Wp1  = (uint16_t*)(ws + 30806016ull);       //     73,728 B
  uint16_t* Wp2  = (uint16_t*)(ws + 30879744ull);       //     73,728 B
  // region B
  uint16_t* Wn   = (uint16_t*)(ws + SZ_BUF);            // 10,616,832 B (f16 w_hi, stride 576)
  uint16_t* Xb   = Wn + (size_t)4 * 2304 * 576;         // 21,233,664 B (f16 [hi|lo], stride 1152)
  uint16_t* Pt2  = (uint16_t*)(ws + SZ_BUF);            // 46,080,000 B (over dead Wn/Xb)
  uint16_t* Rwa  = (uint16_t*)(ws + SZ_BUF + 46080000ull); // 18,874,368 B
  float*    out  = (float*)d_out;

  k_build_wn<<<dim3(2304, 4), 64, 0, stream>>>(b, Wn);
  k_build_x<<<dim3(2304, 4), 64, 0, stream>>>(f, Xb);
  k_gemm_corr<<<dim3(18, 18, 4), 256, 0, stream>>>(Xb, Wn, Yt);   // A=Xb (1152) -> rows=s
  k_zero_pad<<<dim3(196, 4), 256, 0, stream>>>(Pt2);              // Wn/Xb dead now
  k_build_rwa<<<dim3(36, 4), 256, 0, stream>>>(b, Rwa);
  k_fuse_sm<<<dim3(288, 4), 256, 0, stream>>>(Yt, Pt2);
  k_deconv2<<<dim3(20, 8, 4), 256, 0, stream>>>(Rwa, Pt2, T);     // Yt dead now
  k_zero2<<<dim3(2401), 256, 0, stream>>>(Ybt2);                  // zeroes Ybt2+Y1t2 (contiguous)
  k_dred2<<<dim3(48, 4, 4), 64, 0, stream>>>(T, Ybt2);
  k_pack_w<<<dim3(144), 256, 0, stream>>>(w1, w2, Wp1, Wp2);
  k_conv_gemm2<<<dim3(72, 1, 4), 256, 0, stream>>>(Wp1, Ybt2, b1, Y1t2, nullptr);
  k_conv_gemm2<<<dim3(72, 1, 4), 256, 0, stream>>>(Wp2, Y1t2, b2, nullptr, out);
}

// Round 11
// 428.648 us; speedup vs baseline: 1.2651x; 1.1918x over previous
//
#include <hip/hip_runtime.h>
#include <stdint.h>

// ContextualAttention on MI355X. Inputs/outputs float32; correlation logits via
// 2-term f16 split MFMA (A=[x_hi|x_lo] K=1152, B=w_hi staged twice), bf16 MFMA
// elsewhere, fp32 fuse/softmax.
//
// Round 11: fuse_sm reverted to round-8 single-s form (batching regressed: FETCH
// 160->385 MB) + XCD-aware s remap s=(bx&7)*288+(bx>>3): each XCD owns a contiguous
// 288-s window -> sliding ~1 MB row band per XCD L2.
//
// ws layout (bytes), total <= 169,869,312:
//  region A [0, 84934656):
//    phase1: Yt f32 (84,934,656)
//    phase2: T bf16 [0, 20971520) | Ybt2 [20971520, +4917248) | Y1t2 [25888768, +4917248)
//            | Wp1 [30806016, +73728) | Wp2 [30879744, +73728)
//  region B [84934656, ...):
//    phase1: Wn f16 (10,616,832) + Xb f16 (21,233,664)
//    phase2: Pt2 bf16 [SZ_BUF, +46080000) | Rwa [+46080000, +18874368)

#define SZ_BUF 84934656ull
typedef __attribute__((ext_vector_type(8))) short short8;
typedef __attribute__((ext_vector_type(8))) _Float16 half8;
typedef __attribute__((ext_vector_type(4))) float f32x4;
typedef __attribute__((ext_vector_type(4), aligned(4))) float f32x4u;
typedef __attribute__((ext_vector_type(4))) short s16x4;

#if defined(__has_builtin)
#if __has_builtin(__builtin_amdgcn_global_load_lds)
#define HAVE_GLL 1
#endif
#endif

#ifdef HAVE_GLL
typedef const __attribute__((address_space(1))) void* gp1_t;
typedef __attribute__((address_space(3))) void* lp3_t;
__device__ __forceinline__ void gl_lds16(const void* g, void* l){
  __builtin_amdgcn_global_load_lds((gp1_t)g, (lp3_t)l, 16, 0, 0);
}
#else
__device__ __forceinline__ void gl_lds16(const void* g, void* l){
  *(short8*)l = *(const short8*)g;
}
#endif

__device__ __forceinline__ float b2f(uint16_t u){
  union { uint32_t i; float f; } v; v.i = ((uint32_t)u) << 16; return v.f;
}
__device__ __forceinline__ uint16_t f2b(float f){
  uint32_t x = __float_as_uint(f);
  uint32_t r = (x + 0x7FFFu + ((x >> 16) & 1u)) >> 16;
  return (uint16_t)r;
}
__device__ __forceinline__ uint16_t f2h(float f){
  union { _Float16 h; uint16_t u; } v; v.h = (_Float16)f; return v.u;
}
__device__ __forceinline__ float h2f(uint16_t u){
  union { uint16_t u; _Float16 h; } v; v.u = u; return (float)v.h;
}
__device__ __forceinline__ int gfun(int x, int d){
  int t = (x % 48) * 48 + (x / 48) + d;
  if ((unsigned)t >= 2304u) return -1;
  return (t % 48) * 48 + (t / 48);
}

// ---------------- prep kernels (LDS-staged coalesced stores) ----------------

__global__ void k_build_wn(const float* __restrict__ bsrc, uint16_t* __restrict__ wn){
  __shared__ uint16_t lds[576];
  int o = blockIdx.x, item = blockIdx.y, c = threadIdx.x;
  int m = o * 64 + c;
  int c0 = m / 2304, rem = m % 2304, i = rem / 48, j = rem % 48;
  const float* bp = bsrc + ((size_t)item * 64 + c0) * 9216;
  float v[9]; float ss = 0.f;
#pragma unroll
  for (int p = 0; p < 3; p++)
#pragma unroll
    for (int q = 0; q < 3; q++){
      int y = i + p - 1, x = j + q - 1;
      float val = 0.f;
      if ((unsigned)y < 48u && (unsigned)x < 48u) val = bp[y * 192 + x * 2];
      v[p * 3 + q] = val; ss += val * val;
    }
#pragma unroll
  for (int off = 32; off > 0; off >>= 1) ss += __shfl_xor(ss, off, 64);
  float inv = 1.f / fmaxf(sqrtf(ss), 1e-4f);
#pragma unroll
  for (int t = 0; t < 9; t++) lds[c * 9 + t] = f2h(v[t] * inv);
  __syncthreads();
  uint32_t* d32 = (uint32_t*)(wn + ((size_t)item * 2304 + o) * 576);
  const uint32_t* s32 = (const uint32_t*)lds;
#pragma unroll
  for (int k = 0; k < 5; k++){
    int idx = k * 64 + c;
    if (idx < 288) d32[idx] = s32[idx];
  }
}

__global__ void k_build_x(const float* __restrict__ fsrc, uint16_t* __restrict__ xb){
  __shared__ uint16_t lds[1152];
  int s = blockIdx.x, item = blockIdx.y, c = threadIdx.x;
  int y = s / 48, x = s % 48;
  const float* fp = fsrc + ((size_t)item * 64 + c) * 9216;
#pragma unroll
  for (int p = 0; p < 3; p++)
#pragma unroll
    for (int q = 0; q < 3; q++){
      int yy = y + p - 1, xx = x + q - 1;
      float val = 0.f;
      if ((unsigned)yy < 48u && (unsigned)xx < 48u) val = fp[yy * 192 + xx * 2];
      uint16_t hi = f2h(val);
      int t = p * 3 + q;
      lds[c * 9 + t] = hi;
      lds[576 + c * 9 + t] = f2h(val - h2f(hi));
    }
  __syncthreads();
  uint32_t* d32 = (uint32_t*)(xb + ((size_t)item * 2304 + s) * 1152);
  const uint32_t* s32 = (const uint32_t*)lds;
#pragma unroll
  for (int k = 0; k < 9; k++){
    int idx = k * 64 + c;
    d32[idx] = s32[idx];
  }
}

// ---------------- correlation GEMM: Yt[s][o] = X @ Wn^T, M=N=2304, K=1152 (f16) ----------------

__launch_bounds__(256)
__global__ void k_gemm_corr(const uint16_t* __restrict__ A, const uint16_t* __restrict__ B,
                            float* __restrict__ Cd){
  __shared__ __align__(16) uint16_t As[128 * 32];
  __shared__ __align__(16) uint16_t Bs[128 * 32];
  int item = blockIdx.z;
  int n0 = blockIdx.x * 128, m0 = blockIdx.y * 128;
  const uint16_t* Ap = A + (size_t)item * 2304 * 1152;
  const uint16_t* Bp = B + (size_t)item * 2304 * 576;
  int tid = threadIdx.x;
  int wave = tid >> 6, lane = tid & 63, lm = lane & 15, lg = lane >> 4;
  int wy = wave >> 1, wx = wave & 1;
  int swl = (lg ^ ((lm >> 2) & 3)) * 8;
  f32x4 acc[4][4] = {};
  for (int kt = 0; kt < 36; kt++){
    int kb = kt * 32;
    int bkb = (kt < 18) ? kb : kb - 576;
#pragma unroll
    for (int c = tid; c < 1024; c += 256){
      int cc = c & 511;
      int row = cc >> 2, j = cc & 3;
      int sw = (j ^ ((row >> 2) & 3)) * 8;
      if (c < 512)
        gl_lds16(&Ap[(size_t)(m0 + row) * 1152 + kb + sw], &As[cc * 8]);
      else
        gl_lds16(&Bp[(size_t)(n0 + row) * 576 + bkb + sw], &Bs[cc * 8]);
    }
    __syncthreads();
    half8 af[4], bf[4];
#pragma unroll
    for (int i = 0; i < 4; i++){
      af[i] = *(const half8*)&As[(wy * 64 + i * 16 + lm) * 32 + swl];
      bf[i] = *(const half8*)&Bs[(wx * 64 + i * 16 + lm) * 32 + swl];
    }
#pragma unroll
    for (int i = 0; i < 4; i++)
#pragma unroll
      for (int j = 0; j < 4; j++)
        acc[i][j] = __builtin_amdgcn_mfma_f32_16x16x32_f16(af[i], bf[j], acc[i][j], 0, 0, 0);
    __syncthreads();
  }
  float* Cp = Cd + (size_t)item * 2304 * 2304;
#pragma unroll
  for (int i = 0; i < 4; i++){
    int rb = m0 + wy * 64 + i * 16 + lg * 4;
#pragma unroll
    for (int j = 0; j < 4; j++){
      int cc = n0 + wx * 64 + j * 16 + lm;
#pragma unroll
      for (int r = 0; r < 4; r++)
        Cp[(size_t)(rb + r) * 2304 + cc] = acc[i][j][r];
    }
  }
}

// ---------------- merged fuse + softmax (vectorized, XCD-aware s remap) ----------------

__global__ void k_fuse_sm(const float* __restrict__ Yt, uint16_t* __restrict__ pt2){
  __shared__ float red[4];
  int bx = blockIdx.x;
  int s = (bx & 7) * 288 + (bx >> 3);   // XCD k owns contiguous s-window [288k, 288k+288)
  int item = blockIdx.y, t = threadIdx.x;
  const float* yp = Yt + (size_t)item * 2304 * 2304;
  int rs[3]; rs[0] = gfun(s, -1); rs[1] = s; rs[2] = gfun(s, 1);
  int nact = (t < 64) ? 3 : 2;
  f32x4u v[3];
  for (int u = 0; u < 3; u++){
    f32x4u acc = {0.f, 0.f, 0.f, 0.f};
    if (u < nact){
      int g = t + u * 256;
      int o0 = 4 * g, orr = o0 / 48, oc0 = o0 % 48;
#pragma unroll
      for (int dd = 0; dd < 3; dd++){
        int a0 = rs[dd];
        if (a0 < 0) continue;
        int d = dd - 1;
        int base; int vm = 0xF;
        if (d == 0) base = o0;
        else {
          int tor = orr + d;
          if ((unsigned)tor < 48u) base = tor * 48 + oc0;
          else if (tor < 0){ base = 2255 + oc0; if (oc0 == 0) vm = 0xE; }
          else { base = oc0 + 1; if (oc0 == 44) vm = 0x7; }
        }
#pragma unroll
        for (int e = -1; e <= 1; e++){
          int a = a0 + e;
          if ((unsigned)a >= 2304u) continue;
          int cb = base + e;
          const float* rowp = yp + (size_t)a * 2304;
          if (vm == 0xF && cb >= 0 && cb + 3 < 2304){
            acc += *(const f32x4u*)&rowp[cb];
          } else {
#pragma unroll
            for (int i = 0; i < 4; i++)
              if ((vm >> i) & 1){
                int c2 = cb + i;
                if ((unsigned)c2 < 2304u) acc[i] += rowp[c2];
              }
          }
        }
      }
    }
    v[u] = acc;
  }
  float mx = -3.4e38f;
  for (int u = 0; u < nact; u++)
#pragma unroll
    for (int i = 0; i < 4; i++) mx = fmaxf(mx, v[u][i]);
#pragma unroll
  for (int off = 32; off > 0; off >>= 1) mx = fmaxf(mx, __shfl_xor(mx, off, 64));
  if ((t & 63) == 0) red[t >> 6] = mx;
  __syncthreads();
  mx = fmaxf(fmaxf(red[0], red[1]), fmaxf(red[2], red[3]));
  float sum = 0.f;
  for (int u = 0; u < nact; u++)
#pragma unroll
    for (int i = 0; i < 4; i++){ v[u][i] = __expf(10.f * (v[u][i] - mx)); sum += v[u][i]; }
#pragma unroll
  for (int off = 32; off > 0; off >>= 1) sum += __shfl_xor(sum, off, 64);
  __syncthreads();
  if ((t & 63) == 0) red[t >> 6] = sum;
  __syncthreads();
  float inv = 1.f / (red[0] + red[1] + red[2] + red[3]);
  uint16_t* pr = pt2 + ((size_t)item * 2500 + (size_t)(s / 48 + 1) * 50 + (s % 48) + 1) * 2304;
  for (int u = 0; u < nact; u++){
    s16x4 w;
#pragma unroll
    for (int i = 0; i < 4; i++) w[i] = (short)f2b(v[u][i] * inv);
    *(s16x4*)&pr[4 * (t + u * 256)] = w;
  }
}

__global__ void k_zero_pad(uint16_t* __restrict__ pt2){
  int p = blockIdx.x, item = blockIdx.y, t = threadIdx.x;
  int sy, sx;
  if (p < 50){ sy = 0; sx = p; }
  else if (p < 100){ sy = 49; sx = p - 50; }
  else if (p < 148){ sy = p - 99; sx = 0; }
  else { sy = p - 147; sx = 49; }
  uint16_t* pr = pt2 + ((size_t)item * 2500 + sy * 50 + sx) * 2304;
  short8 z = {};
  for (int c = t; c < 288; c += 256) *(short8*)&pr[c * 8] = z;
}

// ---------------- raw 4x4 patch bank, layout [item][tap16][co][l] ----------------

__global__ void k_build_rwa(const float* __restrict__ bsrc, uint16_t* __restrict__ rwa){
  __shared__ uint16_t tile[64][66];
  int item = blockIdx.y, l0 = blockIdx.x * 64;
  const float* bp = bsrc + (size_t)item * 64 * 9216;
  int wave = threadIdx.x >> 6, lane = threadIdx.x & 63;
  for (int tap = 0; tap < 16; tap++){
    int py = tap >> 2, qx = tap & 3;
#pragma unroll
    for (int step = 0; step < 16; step++){
      int lsub = wave * 16 + step;
      int l = l0 + lsub, co = lane;
      int m = l * 64 + co;
      int c0 = m / 2304, rem = m % 2304, i = rem / 48, jj = rem % 48;
      int Y = 2 * i + py - 1, X = 2 * jj + qx - 1;
      float val = 0.f;
      if ((unsigned)Y < 96u && (unsigned)X < 96u) val = bp[(size_t)c0 * 9216 + Y * 96 + X];
      tile[lsub][co] = f2b(val);
    }
    __syncthreads();
#pragma unroll
    for (int step = 0; step < 16; step++){
      int co = wave * 16 + step;
      rwa[(((size_t)item * 16 + tap) * 64 + co) * 2304 + l0 + lane] = tile[lane][co];
    }
    __syncthreads();
  }
}

// ---------------- deconv GEMM: T[m=tap*64+co][sp] = Rwa . Pt2^T, M=1024,N=2560,K=2304 ----------------

__launch_bounds__(256)
__global__ void k_deconv2(const uint16_t* __restrict__ rwa, const uint16_t* __restrict__ pt2,
                          uint16_t* __restrict__ T){
  __shared__ __align__(16) uint16_t As[128 * 32];
  __shared__ __align__(16) uint16_t Bs[128 * 32];
  int item = blockIdx.z;
  int n0 = blockIdx.x * 128, m0 = blockIdx.y * 128;
  const uint16_t* Ap = rwa + (size_t)item * 1024 * 2304;
  const uint16_t* Bp = pt2 + (size_t)item * 2500 * 2304;   // rows up to 2559 read garbage; discarded
  int tid = threadIdx.x;
  int wave = tid >> 6, lane = tid & 63, lm = lane & 15, lg = lane >> 4;
  int wy = wave >> 1, wx = wave & 1;
  int swl = (lg ^ ((lm >> 2) & 3)) * 8;
  f32x4 acc[4][4] = {};
  for (int kt = 0; kt < 72; kt++){
    int kb = kt * 32;
#pragma unroll
    for (int c = tid; c < 1024; c += 256){
      int cc = c & 511;
      int row = cc >> 2, j = cc & 3;
      int sw = (j ^ ((row >> 2) & 3)) * 8;
      if (c < 512)
        gl_lds16(&Ap[(size_t)(m0 + row) * 2304 + kb + sw], &As[cc * 8]);
      else
        gl_lds16(&Bp[(size_t)(n0 + row) * 2304 + kb + sw], &Bs[cc * 8]);
    }
    __syncthreads();
    short8 af[4], bf[4];
#pragma unroll
    for (int i = 0; i < 4; i++){
      af[i] = *(const short8*)&As[(wy * 64 + i * 16 + lm) * 32 + swl];
      bf[i] = *(const short8*)&Bs[(wx * 64 + i * 16 + lm) * 32 + swl];
    }
#pragma unroll
    for (int i = 0; i < 4; i++)
#pragma unroll
      for (int j = 0; j < 4; j++)
        acc[i][j] = __builtin_amdgcn_mfma_f32_16x16x32_bf16(af[i], bf[j], acc[i][j], 0, 0, 0);
    __syncthreads();
  }
  uint16_t* Tp = T + (size_t)item * 1024 * 2560;
#pragma unroll
  for (int i = 0; i < 4; i++){
    int rb = m0 + wy * 64 + i * 16 + lg * 4;
#pragma unroll
    for (int j = 0; j < 4; j++){
      int cc = n0 + wx * 64 + j * 16 + lm;
#pragma unroll
      for (int r = 0; r < 4; r++)
        Tp[(size_t)(rb + r) * 2560 + cc] = f2b(acc[i][j][r]);
    }
  }
}

// gather 4 taps per output pixel -> padded Ybt2[98][98][64] interior
__global__ void k_dred2(const uint16_t* __restrict__ T, uint16_t* __restrict__ ybt2){
  int my = blockIdx.x, phase = blockIdx.y, item = blockIdx.z;
  int co = threadIdx.x;
  int fy = phase >> 1, fx = phase & 1;
  const uint16_t* Tp = T + (size_t)item * 1024 * 2560;
  uint16_t* op = ybt2 + (size_t)item * 98 * 98 * 64;
  for (int mx = 0; mx < 48; mx++){
    float acc = 0.f;
#pragma unroll
    for (int ay = 0; ay < 2; ay++)
#pragma unroll
      for (int ax = 0; ax < 2; ax++){
        int tap = (3 - fy - 2 * ay) * 4 + (3 - fx - 2 * ax);
        int sp = (my + ay + fy) * 50 + (mx + ax + fx);
        acc += b2f(Tp[(size_t)(tap * 64 + co) * 2560 + sp]);
      }
    int Y = 2 * my + fy + 1, X = 2 * mx + fx + 1;
    op[((size_t)Y * 98 + X) * 64 + co] = f2b(acc * 0.25f);
  }
}

__global__ void k_zero2(uint16_t* __restrict__ p){
  size_t i = ((size_t)blockIdx.x * 256 + threadIdx.x) * 8;
  short8 z = {};
  *(short8*)&p[i] = z;
}

// ---------------- final 3x3 convs (direct from padded layout) ----------------

__global__ void k_pack_w(const float* __restrict__ w1, const float* __restrict__ w2,
                         uint16_t* __restrict__ p1, uint16_t* __restrict__ p2){
  int i = blockIdx.x * 256 + threadIdx.x;
  if (i < 36864){
    int co = i / 576, rem = i % 576, ci = rem / 9, t = rem % 9;
    int di = co * 576 + t * 64 + ci;
    p1[di] = f2b(w1[i]); p2[di] = f2b(w2[i]);
  }
}

__launch_bounds__(256)
__global__ void k_conv_gemm2(const uint16_t* __restrict__ Wp, const uint16_t* __restrict__ Src,
                             const float* __restrict__ bias,
                             uint16_t* __restrict__ dst16, float* __restrict__ dst32){
  __shared__ __align__(16) uint16_t As[64 * 32];
  __shared__ __align__(16) uint16_t Bs[128 * 32];
  int n0 = blockIdx.x * 128, item = blockIdx.z;
  int tid = threadIdx.x, wave = tid >> 6, lane = tid & 63, lm = lane & 15, lg = lane >> 4;
  int swl = (lg ^ ((lm >> 2) & 3)) * 8;
  const uint16_t* Bp = Src + (size_t)item * 98 * 98 * 64;
  f32x4 acc[4][2] = {};
  for (int kt = 0; kt < 18; kt++){
    int t = kt >> 1, cb = (kt & 1) * 32;
    int py = t / 3, qx = t % 3;
#pragma unroll
    for (int c = tid; c < 768; c += 256){
      if (c < 256){
        int row = c >> 2, j = c & 3;
        int sw = (j ^ ((row >> 2) & 3)) * 8;
        gl_lds16(&Wp[(size_t)row * 576 + kt * 32 + sw], &As[c * 8]);
      } else {
        int cc = c - 256; int row = cc >> 2, j = cc & 3;
        int sw = (j ^ ((row >> 2) & 3)) * 8;
        int n = n0 + row; int y = n / 96, x = n % 96;
        gl_lds16(&Bp[((size_t)(y + py) * 98 + (x + qx)) * 64 + cb + sw], &Bs[cc * 8]);
      }
    }
    __syncthreads();
    short8 af[4], bf[2];
#pragma unroll
    for (int i = 0; i < 4; i++) af[i] = *(const short8*)&As[(i * 16 + lm) * 32 + swl];
#pragma unroll
    for (int j = 0; j < 2; j++) bf[j] = *(const short8*)&Bs[(wave * 32 + j * 16 + lm) * 32 + swl];
#pragma unroll
    for (int i = 0; i < 4; i++)
#pragma unroll
      for (int j = 0; j < 2; j++)
        acc[i][j] = __builtin_amdgcn_mfma_f32_16x16x32_bf16(af[i], bf[j], acc[i][j], 0, 0, 0);
    __syncthreads();
  }
  if (dst32){
#pragma unroll
    for (int i = 0; i < 4; i++)
#pragma unroll
      for (int j = 0; j < 2; j++){
        int n = n0 + wave * 32 + j * 16 + lm;
#pragma unroll
        for (int r = 0; r < 4; r++){
          int co = i * 16 + lg * 4 + r;
          dst32[((size_t)item * 64 + co) * 9216 + n] = acc[i][j][r] + bias[co];
        }
      }
  } else {
    uint16_t* dp = dst16 + (size_t)item * 98 * 98 * 64;
#pragma unroll
    for (int i = 0; i < 4; i++)
#pragma unroll
      for (int j = 0; j < 2; j++){
        int n = n0 + wave * 32 + j * 16 + lm;
        int y = n / 96, x = n % 96;
        int co0 = i * 16 + lg * 4;
        s16x4 w;
#pragma unroll
        for (int r = 0; r < 4; r++) w[r] = (short)f2b(acc[i][j][r] + bias[co0 + r]);
        *(s16x4*)&dp[((size_t)(y + 1) * 98 + (x + 1)) * 64 + co0] = w;
      }
  }
}

// ---------------- launch ----------------

extern "C" void kernel_launch(void* const* d_in, const int* in_sizes, int n_in,
                              void* d_out, int out_size, void* d_ws, size_t ws_size,
                              hipStream_t stream){
  const float* f  = (const float*)d_in[0];
  const float* b  = (const float*)d_in[1];
  const float* w1 = (const float*)d_in[2];
  const float* b1 = (const float*)d_in[3];
  const float* w2 = (const float*)d_in[4];
  const float* b2 = (const float*)d_in[5];
  char* ws = (char*)d_ws;
  // region A
  float*    Yt   = (float*)ws;                          // 84,934,656 B (phase1)
  uint16_t* T    = (uint16_t*)ws;                       // 20,971,520 B (over dead Yt)
  uint16_t* Ybt2 = (uint16_t*)(ws + 20971520ull);       //  4,917,248 B
  uint16_t* Y1t2 = (uint16_t*)(ws + 25888768ull);       //  4,917,248 B
  uint16_t* Wp1  = (uint16_t*)(ws + 30806016ull);       //     73,728 B
  uint16_t* Wp2  = (uint16_t*)(ws + 30879744ull);       //     73,728 B
  // region B
  uint16_t* Wn   = (uint16_t*)(ws + SZ_BUF);            // 10,616,832 B (f16 w_hi, stride 576)
  uint16_t* Xb   = Wn + (size_t)4 * 2304 * 576;         // 21,233,664 B (f16 [hi|lo], stride 1152)
  uint16_t* Pt2  = (uint16_t*)(ws + SZ_BUF);            // 46,080,000 B (over dead Wn/Xb)
  uint16_t* Rwa  = (uint16_t*)(ws + SZ_BUF + 46080000ull); // 18,874,368 B
  float*    out  = (float*)d_out;

  k_build_wn<<<dim3(2304, 4), 64, 0, stream>>>(b, Wn);
  k_build_x<<<dim3(2304, 4), 64, 0, stream>>>(f, Xb);
  k_gemm_corr<<<dim3(18, 18, 4), 256, 0, stream>>>(Xb, Wn, Yt);   // A=Xb (1152) -> rows=s
  k_zero_pad<<<dim3(196, 4), 256, 0, stream>>>(Pt2);              // Wn/Xb dead now
  k_build_rwa<<<dim3(36, 4), 256, 0, stream>>>(b, Rwa);
  k_fuse_sm<<<dim3(2304, 4), 256, 0, stream>>>(Yt, Pt2);
  k_deconv2<<<dim3(20, 8, 4), 256, 0, stream>>>(Rwa, Pt2, T);     // Yt dead now
  k_zero2<<<dim3(2401), 256, 0, stream>>>(Ybt2);                  // zeroes Ybt2+Y1t2 (contiguous)
  k_dred2<<<dim3(48, 4, 4), 64, 0, stream>>>(T, Ybt2);
  k_pack_w<<<dim3(144), 256, 0, stream>>>(w1, w2, Wp1, Wp2);
  k_conv_gemm2<<<dim3(72, 1, 4), 256, 0, stream>>>(Wp1, Ybt2, b1, Y1t2, nullptr);
  k_conv_gemm2<<<dim3(72, 1, 4), 256, 0, stream>>>(Wp2, Y1t2, b2, nullptr, out);
}

// Round 12
// 406.887 us; speedup vs baseline: 1.3328x; 1.0535x over previous
//
#include <hip/hip_runtime.h>
#include <stdint.h>

// ContextualAttention on MI355X. Inputs/outputs float32; correlation logits via
// 2-term f16 split MFMA (A=[x_hi|x_lo], B=w_hi), bf16 MFMA elsewhere, fp32 softmax.
//
// Round 12: more MFMA per barrier.
//  - k_gemm_corr: stage A_hi+A_lo+B per iter (3x8KB LDS), 32 MFMA/barrier, 18 iters
//    (B no longer staged twice).
//  - k_deconv2: BK=64 (32KB LDS), 32 MFMA/barrier, 36 iters; 8-chunk XOR swizzle
//    pj=j^(row&7) (row stride 128B = 0 mod 32 banks -> old parity swizzle useless).
//
// ws layout (bytes), total <= 169,869,312:
//  region A [0, 84934656):
//    phase1: Yt f32 (84,934,656)
//    phase2: T bf16 [0, 20971520) | Ybt2 [20971520, +4917248) | Y1t2 [25888768, +4917248)
//            | Wp1 [30806016, +73728) | Wp2 [30879744, +73728)
//  region B [84934656, ...):
//    phase1: Wn f16 (10,616,832) + Xb f16 (21,233,664)
//    phase2: Pt2 bf16 [SZ_BUF, +46080000) | Rwa [+46080000, +18874368)

#define SZ_BUF 84934656ull
typedef __attribute__((ext_vector_type(8))) short short8;
typedef __attribute__((ext_vector_type(8))) _Float16 half8;
typedef __attribute__((ext_vector_type(4))) float f32x4;
typedef __attribute__((ext_vector_type(4), aligned(4))) float f32x4u;
typedef __attribute__((ext_vector_type(4))) short s16x4;

#if defined(__has_builtin)
#if __has_builtin(__builtin_amdgcn_global_load_lds)
#define HAVE_GLL 1
#endif
#endif

#ifdef HAVE_GLL
typedef const __attribute__((address_space(1))) void* gp1_t;
typedef __attribute__((address_space(3))) void* lp3_t;
__device__ __forceinline__ void gl_lds16(const void* g, void* l){
  __builtin_amdgcn_global_load_lds((gp1_t)g, (lp3_t)l, 16, 0, 0);
}
#else
__device__ __forceinline__ void gl_lds16(const void* g, void* l){
  *(short8*)l = *(const short8*)g;
}
#endif

__device__ __forceinline__ float b2f(uint16_t u){
  union { uint32_t i; float f; } v; v.i = ((uint32_t)u) << 16; return v.f;
}
__device__ __forceinline__ uint16_t f2b(float f){
  uint32_t x = __float_as_uint(f);
  uint32_t r = (x + 0x7FFFu + ((x >> 16) & 1u)) >> 16;
  return (uint16_t)r;
}
__device__ __forceinline__ uint16_t f2h(float f){
  union { _Float16 h; uint16_t u; } v; v.h = (_Float16)f; return v.u;
}
__device__ __forceinline__ float h2f(uint16_t u){
  union { uint16_t u; _Float16 h; } v; v.u = u; return (float)v.h;
}
__device__ __forceinline__ int gfun(int x, int d){
  int t = (x % 48) * 48 + (x / 48) + d;
  if ((unsigned)t >= 2304u) return -1;
  return (t % 48) * 48 + (t / 48);
}

// ---------------- prep kernels (LDS-staged coalesced stores) ----------------

__global__ void k_build_wn(const float* __restrict__ bsrc, uint16_t* __restrict__ wn){
  __shared__ uint16_t lds[576];
  int o = blockIdx.x, item = blockIdx.y, c = threadIdx.x;
  int m = o * 64 + c;
  int c0 = m / 2304, rem = m % 2304, i = rem / 48, j = rem % 48;
  const float* bp = bsrc + ((size_t)item * 64 + c0) * 9216;
  float v[9]; float ss = 0.f;
#pragma unroll
  for (int p = 0; p < 3; p++)
#pragma unroll
    for (int q = 0; q < 3; q++){
      int y = i + p - 1, x = j + q - 1;
      float val = 0.f;
      if ((unsigned)y < 48u && (unsigned)x < 48u) val = bp[y * 192 + x * 2];
      v[p * 3 + q] = val; ss += val * val;
    }
#pragma unroll
  for (int off = 32; off > 0; off >>= 1) ss += __shfl_xor(ss, off, 64);
  float inv = 1.f / fmaxf(sqrtf(ss), 1e-4f);
#pragma unroll
  for (int t = 0; t < 9; t++) lds[c * 9 + t] = f2h(v[t] * inv);
  __syncthreads();
  uint32_t* d32 = (uint32_t*)(wn + ((size_t)item * 2304 + o) * 576);
  const uint32_t* s32 = (const uint32_t*)lds;
#pragma unroll
  for (int k = 0; k < 5; k++){
    int idx = k * 64 + c;
    if (idx < 288) d32[idx] = s32[idx];
  }
}

__global__ void k_build_x(const float* __restrict__ fsrc, uint16_t* __restrict__ xb){
  __shared__ uint16_t lds[1152];
  int s = blockIdx.x, item = blockIdx.y, c = threadIdx.x;
  int y = s / 48, x = s % 48;
  const float* fp = fsrc + ((size_t)item * 64 + c) * 9216;
#pragma unroll
  for (int p = 0; p < 3; p++)
#pragma unroll
    for (int q = 0; q < 3; q++){
      int yy = y + p - 1, xx = x + q - 1;
      float val = 0.f;
      if ((unsigned)yy < 48u && (unsigned)xx < 48u) val = fp[yy * 192 + xx * 2];
      uint16_t hi = f2h(val);
      int t = p * 3 + q;
      lds[c * 9 + t] = hi;
      lds[576 + c * 9 + t] = f2h(val - h2f(hi));
    }
  __syncthreads();
  uint32_t* d32 = (uint32_t*)(xb + ((size_t)item * 2304 + s) * 1152);
  const uint32_t* s32 = (const uint32_t*)lds;
#pragma unroll
  for (int k = 0; k < 9; k++){
    int idx = k * 64 + c;
    d32[idx] = s32[idx];
  }
}

// ---------------- correlation GEMM: Yt[s][o] = X @ Wn^T, M=N=2304, trueK=576 ----------------
// Per iter: stage A_hi, A_lo (from K=1152 [hi|lo] rows) + B (w_hi); 32 MFMA/barrier.

__launch_bounds__(256)
__global__ void k_gemm_corr(const uint16_t* __restrict__ A, const uint16_t* __restrict__ B,
                            float* __restrict__ Cd){
  __shared__ __align__(16) uint16_t As1[128 * 32];
  __shared__ __align__(16) uint16_t As2[128 * 32];
  __shared__ __align__(16) uint16_t Bs[128 * 32];
  int item = blockIdx.z;
  int n0 = blockIdx.x * 128, m0 = blockIdx.y * 128;
  const uint16_t* Ap = A + (size_t)item * 2304 * 1152;
  const uint16_t* Bp = B + (size_t)item * 2304 * 576;
  int tid = threadIdx.x;
  int wave = tid >> 6, lane = tid & 63, lm = lane & 15, lg = lane >> 4;
  int wy = wave >> 1, wx = wave & 1;
  int swl = (lg ^ ((lm >> 2) & 3)) * 8;
  f32x4 acc[4][4] = {};
  for (int kt = 0; kt < 18; kt++){
    int kb = kt * 32;
#pragma unroll
    for (int c = tid; c < 1536; c += 256){
      int half = c >> 9;            // 0=A_hi, 1=A_lo, 2=B
      int cc = c & 511;
      int row = cc >> 2, j = cc & 3;
      int sw = (j ^ ((row >> 2) & 3)) * 8;
      if (half == 0)
        gl_lds16(&Ap[(size_t)(m0 + row) * 1152 + kb + sw], &As1[cc * 8]);
      else if (half == 1)
        gl_lds16(&Ap[(size_t)(m0 + row) * 1152 + 576 + kb + sw], &As2[cc * 8]);
      else
        gl_lds16(&Bp[(size_t)(n0 + row) * 576 + kb + sw], &Bs[cc * 8]);
    }
    __syncthreads();
    half8 af1[4], af2[4], bf[4];
#pragma unroll
    for (int i = 0; i < 4; i++){
      af1[i] = *(const half8*)&As1[(wy * 64 + i * 16 + lm) * 32 + swl];
      af2[i] = *(const half8*)&As2[(wy * 64 + i * 16 + lm) * 32 + swl];
      bf[i]  = *(const half8*)&Bs[(wx * 64 + i * 16 + lm) * 32 + swl];
    }
#pragma unroll
    for (int i = 0; i < 4; i++)
#pragma unroll
      for (int j = 0; j < 4; j++){
        acc[i][j] = __builtin_amdgcn_mfma_f32_16x16x32_f16(af1[i], bf[j], acc[i][j], 0, 0, 0);
        acc[i][j] = __builtin_amdgcn_mfma_f32_16x16x32_f16(af2[i], bf[j], acc[i][j], 0, 0, 0);
      }
    __syncthreads();
  }
  float* Cp = Cd + (size_t)item * 2304 * 2304;
#pragma unroll
  for (int i = 0; i < 4; i++){
    int rb = m0 + wy * 64 + i * 16 + lg * 4;
#pragma unroll
    for (int j = 0; j < 4; j++){
      int cc = n0 + wx * 64 + j * 16 + lm;
#pragma unroll
      for (int r = 0; r < 4; r++)
        Cp[(size_t)(rb + r) * 2304 + cc] = acc[i][j][r];
    }
  }
}

// ---------------- merged fuse + softmax (vectorized, XCD-aware s remap) ----------------

__global__ void k_fuse_sm(const float* __restrict__ Yt, uint16_t* __restrict__ pt2){
  __shared__ float red[4];
  int bx = blockIdx.x;
  int s = (bx & 7) * 288 + (bx >> 3);   // XCD k owns contiguous s-window
  int item = blockIdx.y, t = threadIdx.x;
  const float* yp = Yt + (size_t)item * 2304 * 2304;
  int rs[3]; rs[0] = gfun(s, -1); rs[1] = s; rs[2] = gfun(s, 1);
  int nact = (t < 64) ? 3 : 2;
  f32x4u v[3];
  for (int u = 0; u < 3; u++){
    f32x4u acc = {0.f, 0.f, 0.f, 0.f};
    if (u < nact){
      int g = t + u * 256;
      int o0 = 4 * g, orr = o0 / 48, oc0 = o0 % 48;
#pragma unroll
      for (int dd = 0; dd < 3; dd++){
        int a0 = rs[dd];
        if (a0 < 0) continue;
        int d = dd - 1;
        int base; int vm = 0xF;
        if (d == 0) base = o0;
        else {
          int tor = orr + d;
          if ((unsigned)tor < 48u) base = tor * 48 + oc0;
          else if (tor < 0){ base = 2255 + oc0; if (oc0 == 0) vm = 0xE; }
          else { base = oc0 + 1; if (oc0 == 44) vm = 0x7; }
        }
#pragma unroll
        for (int e = -1; e <= 1; e++){
          int a = a0 + e;
          if ((unsigned)a >= 2304u) continue;
          int cb = base + e;
          const float* rowp = yp + (size_t)a * 2304;
          if (vm == 0xF && cb >= 0 && cb + 3 < 2304){
            acc += *(const f32x4u*)&rowp[cb];
          } else {
#pragma unroll
            for (int i = 0; i < 4; i++)
              if ((vm >> i) & 1){
                int c2 = cb + i;
                if ((unsigned)c2 < 2304u) acc[i] += rowp[c2];
              }
          }
        }
      }
    }
    v[u] = acc;
  }
  float mx = -3.4e38f;
  for (int u = 0; u < nact; u++)
#pragma unroll
    for (int i = 0; i < 4; i++) mx = fmaxf(mx, v[u][i]);
#pragma unroll
  for (int off = 32; off > 0; off >>= 1) mx = fmaxf(mx, __shfl_xor(mx, off, 64));
  if ((t & 63) == 0) red[t >> 6] = mx;
  __syncthreads();
  mx = fmaxf(fmaxf(red[0], red[1]), fmaxf(red[2], red[3]));
  float sum = 0.f;
  for (int u = 0; u < nact; u++)
#pragma unroll
    for (int i = 0; i < 4; i++){ v[u][i] = __expf(10.f * (v[u][i] - mx)); sum += v[u][i]; }
#pragma unroll
  for (int off = 32; off > 0; off >>= 1) sum += __shfl_xor(sum, off, 64);
  __syncthreads();
  if ((t & 63) == 0) red[t >> 6] = sum;
  __syncthreads();
  float inv = 1.f / (red[0] + red[1] + red[2] + red[3]);
  uint16_t* pr = pt2 + ((size_t)item * 2500 + (size_t)(s / 48 + 1) * 50 + (s % 48) + 1) * 2304;
  for (int u = 0; u < nact; u++){
    s16x4 w;
#pragma unroll
    for (int i = 0; i < 4; i++) w[i] = (short)f2b(v[u][i] * inv);
    *(s16x4*)&pr[4 * (t + u * 256)] = w;
  }
}

__global__ void k_zero_pad(uint16_t* __restrict__ pt2){
  int p = blockIdx.x, item = blockIdx.y, t = threadIdx.x;
  int sy, sx;
  if (p < 50){ sy = 0; sx = p; }
  else if (p < 100){ sy = 49; sx = p - 50; }
  else if (p < 148){ sy = p - 99; sx = 0; }
  else { sy = p - 147; sx = 49; }
  uint16_t* pr = pt2 + ((size_t)item * 2500 + sy * 50 + sx) * 2304;
  short8 z = {};
  for (int c = t; c < 288; c += 256) *(short8*)&pr[c * 8] = z;
}

// ---------------- raw 4x4 patch bank, layout [item][tap16][co][l] ----------------

__global__ void k_build_rwa(const float* __restrict__ bsrc, uint16_t* __restrict__ rwa){
  __shared__ uint16_t tile[64][66];
  int item = blockIdx.y, l0 = blockIdx.x * 64;
  const float* bp = bsrc + (size_t)item * 64 * 9216;
  int wave = threadIdx.x >> 6, lane = threadIdx.x & 63;
  for (int tap = 0; tap < 16; tap++){
    int py = tap >> 2, qx = tap & 3;
#pragma unroll
    for (int step = 0; step < 16; step++){
      int lsub = wave * 16 + step;
      int l = l0 + lsub, co = lane;
      int m = l * 64 + co;
      int c0 = m / 2304, rem = m % 2304, i = rem / 48, jj = rem % 48;
      int Y = 2 * i + py - 1, X = 2 * jj + qx - 1;
      float val = 0.f;
      if ((unsigned)Y < 96u && (unsigned)X < 96u) val = bp[(size_t)c0 * 9216 + Y * 96 + X];
      tile[lsub][co] = f2b(val);
    }
    __syncthreads();
#pragma unroll
    for (int step = 0; step < 16; step++){
      int co = wave * 16 + step;
      rwa[(((size_t)item * 16 + tap) * 64 + co) * 2304 + l0 + lane] = tile[lane][co];
    }
    __syncthreads();
  }
}

// ---------------- deconv GEMM: T = Rwa . Pt2^T, M=1024,N=2560,K=2304, BK=64 ----------------

__launch_bounds__(256)
__global__ void k_deconv2(const uint16_t* __restrict__ rwa, const uint16_t* __restrict__ pt2,
                          uint16_t* __restrict__ T){
  __shared__ __align__(16) uint16_t As[128 * 64];
  __shared__ __align__(16) uint16_t Bs[128 * 64];
  int item = blockIdx.z;
  int n0 = blockIdx.x * 128, m0 = blockIdx.y * 128;
  const uint16_t* Ap = rwa + (size_t)item * 1024 * 2304;
  const uint16_t* Bp = pt2 + (size_t)item * 2500 * 2304;   // rows >= 2500 read garbage; discarded
  int tid = threadIdx.x;
  int wave = tid >> 6, lane = tid & 63, lm = lane & 15, lg = lane >> 4;
  int wy = wave >> 1, wx = wave & 1;
  f32x4 acc[4][4] = {};
  for (int kt = 0; kt < 36; kt++){
    int kb = kt * 64;
#pragma unroll
    for (int c = tid; c < 2048; c += 256){
      int cc = c & 1023;
      int row = cc >> 3, pj = cc & 7;
      int jl = pj ^ (row & 7);           // 8-chunk XOR swizzle
      if (c < 1024)
        gl_lds16(&Ap[(size_t)(m0 + row) * 2304 + kb + jl * 8], &As[cc * 8]);
      else
        gl_lds16(&Bp[(size_t)(n0 + row) * 2304 + kb + jl * 8], &Bs[cc * 8]);
    }
    __syncthreads();
#pragma unroll
    for (int k2 = 0; k2 < 2; k2++){
      short8 af[4], bf[4];
#pragma unroll
      for (int i = 0; i < 4; i++){
        int rowa = wy * 64 + i * 16 + lm;
        int pja = (k2 * 4 + lg) ^ (lm & 7);
        af[i] = *(const short8*)&As[rowa * 64 + pja * 8];
        int rowb = wx * 64 + i * 16 + lm;
        bf[i] = *(const short8*)&Bs[rowb * 64 + pja * 8];
      }
#pragma unroll
      for (int i = 0; i < 4; i++)
#pragma unroll
        for (int j = 0; j < 4; j++)
          acc[i][j] = __builtin_amdgcn_mfma_f32_16x16x32_bf16(af[i], bf[j], acc[i][j], 0, 0, 0);
    }
    __syncthreads();
  }
  uint16_t* Tp = T + (size_t)item * 1024 * 2560;
#pragma unroll
  for (int i = 0; i < 4; i++){
    int rb = m0 + wy * 64 + i * 16 + lg * 4;
#pragma unroll
    for (int j = 0; j < 4; j++){
      int cc = n0 + wx * 64 + j * 16 + lm;
#pragma unroll
      for (int r = 0; r < 4; r++)
        Tp[(size_t)(rb + r) * 2560 + cc] = f2b(acc[i][j][r]);
    }
  }
}

// gather 4 taps per output pixel -> padded Ybt2[98][98][64] interior
__global__ void k_dred2(const uint16_t* __restrict__ T, uint16_t* __restrict__ ybt2){
  int my = blockIdx.x, phase = blockIdx.y, item = blockIdx.z;
  int co = threadIdx.x;
  int fy = phase >> 1, fx = phase & 1;
  const uint16_t* Tp = T + (size_t)item * 1024 * 2560;
  uint16_t* op = ybt2 + (size_t)item * 98 * 98 * 64;
  for (int mx = 0; mx < 48; mx++){
    float acc = 0.f;
#pragma unroll
    for (int ay = 0; ay < 2; ay++)
#pragma unroll
      for (int ax = 0; ax < 2; ax++){
        int tap = (3 - fy - 2 * ay) * 4 + (3 - fx - 2 * ax);
        int sp = (my + ay + fy) * 50 + (mx + ax + fx);
        acc += b2f(Tp[(size_t)(tap * 64 + co) * 2560 + sp]);
      }
    int Y = 2 * my + fy + 1, X = 2 * mx + fx + 1;
    op[((size_t)Y * 98 + X) * 64 + co] = f2b(acc * 0.25f);
  }
}

__global__ void k_zero2(uint16_t* __restrict__ p){
  size_t i = ((size_t)blockIdx.x * 256 + threadIdx.x) * 8;
  short8 z = {};
  *(short8*)&p[i] = z;
}

// ---------------- final 3x3 convs (direct from padded layout) ----------------

__global__ void k_pack_w(const float* __restrict__ w1, const float* __restrict__ w2,
                         uint16_t* __restrict__ p1, uint16_t* __restrict__ p2){
  int i = blockIdx.x * 256 + threadIdx.x;
  if (i < 36864){
    int co = i / 576, rem = i % 576, ci = rem / 9, t = rem % 9;
    int di = co * 576 + t * 64 + ci;
    p1[di] = f2b(w1[i]); p2[di] = f2b(w2[i]);
  }
}

__launch_bounds__(256)
__global__ void k_conv_gemm2(const uint16_t* __restrict__ Wp, const uint16_t* __restrict__ Src,
                             const float* __restrict__ bias,
                             uint16_t* __restrict__ dst16, float* __restrict__ dst32){
  __shared__ __align__(16) uint16_t As[64 * 32];
  __shared__ __align__(16) uint16_t Bs[128 * 32];
  int n0 = blockIdx.x * 128, item = blockIdx.z;
  int tid = threadIdx.x, wave = tid >> 6, lane = tid & 63, lm = lane & 15, lg = lane >> 4;
  int swl = (lg ^ ((lm >> 2) & 3)) * 8;
  const uint16_t* Bp = Src + (size_t)item * 98 * 98 * 64;
  f32x4 acc[4][2] = {};
  for (int kt = 0; kt < 18; kt++){
    int t = kt >> 1, cb = (kt & 1) * 32;
    int py = t / 3, qx = t % 3;
#pragma unroll
    for (int c = tid; c < 768; c += 256){
      if (c < 256){
        int row = c >> 2, j = c & 3;
        int sw = (j ^ ((row >> 2) & 3)) * 8;
        gl_lds16(&Wp[(size_t)row * 576 + kt * 32 + sw], &As[c * 8]);
      } else {
        int cc = c - 256; int row = cc >> 2, j = cc & 3;
        int sw = (j ^ ((row >> 2) & 3)) * 8;
        int n = n0 + row; int y = n / 96, x = n % 96;
        gl_lds16(&Bp[((size_t)(y + py) * 98 + (x + qx)) * 64 + cb + sw], &Bs[cc * 8]);
      }
    }
    __syncthreads();
    short8 af[4], bf[2];
#pragma unroll
    for (int i = 0; i < 4; i++) af[i] = *(const short8*)&As[(i * 16 + lm) * 32 + swl];
#pragma unroll
    for (int j = 0; j < 2; j++) bf[j] = *(const short8*)&Bs[(wave * 32 + j * 16 + lm) * 32 + swl];
#pragma unroll
    for (int i = 0; i < 4; i++)
#pragma unroll
      for (int j = 0; j < 2; j++)
        acc[i][j] = __builtin_amdgcn_mfma_f32_16x16x32_bf16(af[i], bf[j], acc[i][j], 0, 0, 0);
    __syncthreads();
  }
  if (dst32){
#pragma unroll
    for (int i = 0; i < 4; i++)
#pragma unroll
      for (int j = 0; j < 2; j++){
        int n = n0 + wave * 32 + j * 16 + lm;
#pragma unroll
        for (int r = 0; r < 4; r++){
          int co = i * 16 + lg * 4 + r;
          dst32[((size_t)item * 64 + co) * 9216 + n] = acc[i][j][r] + bias[co];
        }
      }
  } else {
    uint16_t* dp = dst16 + (size_t)item * 98 * 98 * 64;
#pragma unroll
    for (int i = 0; i < 4; i++)
#pragma unroll
      for (int j = 0; j < 2; j++){
        int n = n0 + wave * 32 + j * 16 + lm;
        int y = n / 96, x = n % 96;
        int co0 = i * 16 + lg * 4;
        s16x4 w;
#pragma unroll
        for (int r = 0; r < 4; r++) w[r] = (short)f2b(acc[i][j][r] + bias[co0 + r]);
        *(s16x4*)&dp[((size_t)(y + 1) * 98 + (x + 1)) * 64 + co0] = w;
      }
  }
}

// ---------------- launch ----------------

extern "C" void kernel_launch(void* const* d_in, const int* in_sizes, int n_in,
                              void* d_out, int out_size, void* d_ws, size_t ws_size,
                              hipStream_t stream){
  const float* f  = (const float*)d_in[0];
  const float* b  = (const float*)d_in[1];
  const float* w1 = (const float*)d_in[2];
  const float* b1 = (const float*)d_in[3];
  const float* w2 = (const float*)d_in[4];
  const float* b2 = (const float*)d_in[5];
  char* ws = (char*)d_ws;
  // region A
  float*    Yt   = (float*)ws;                          // 84,934,656 B (phase1)
  uint16_t* T    = (uint16_t*)ws;                       // 20,971,520 B (over dead Yt)
  uint16_t* Ybt2 = (uint16_t*)(ws + 20971520ull);       //  4,917,248 B
  uint16_t* Y1t2 = (uint16_t*)(ws + 25888768ull);       //  4,917,248 B
  uint16_t* Wp1  = (uint16_t*)(ws + 30806016ull);       //     73,728 B
  uint16_t* Wp2  = (uint16_t*)(ws + 30879744ull);       //     73,728 B
  // region B
  uint16_t* Wn   = (uint16_t*)(ws + SZ_BUF);            // 10,616,832 B (f16 w_hi, stride 576)
  uint16_t* Xb   = Wn + (size_t)4 * 2304 * 576;         // 21,233,664 B (f16 [hi|lo], stride 1152)
  uint16_t* Pt2  = (uint16_t*)(ws + SZ_BUF);            // 46,080,000 B (over dead Wn/Xb)
  uint16_t* Rwa  = (uint16_t*)(ws + SZ_BUF + 46080000ull); // 18,874,368 B
  float*    out  = (float*)d_out;

  k_build_wn<<<dim3(2304, 4), 64, 0, stream>>>(b, Wn);
  k_build_x<<<dim3(2304, 4), 64, 0, stream>>>(f, Xb);
  k_gemm_corr<<<dim3(18, 18, 4), 256, 0, stream>>>(Xb, Wn, Yt);   // A=Xb (1152) -> rows=s
  k_zero_pad<<<dim3(196, 4), 256, 0, stream>>>(Pt2);              // Wn/Xb dead now
  k_build_rwa<<<dim3(36, 4), 256, 0, stream>>>(b, Rwa);
  k_fuse_sm<<<dim3(2304, 4), 256, 0, stream>>>(Yt, Pt2);
  k_deconv2<<<dim3(20, 8, 4), 256, 0, stream>>>(Rwa, Pt2, T);     // Yt dead now
  k_zero2<<<dim3(2401), 256, 0, stream>>>(Ybt2);                  // zeroes Ybt2+Y1t2 (contiguous)
  k_dred2<<<dim3(48, 4, 4), 64, 0, stream>>>(T, Ybt2);
  k_pack_w<<<dim3(144), 256, 0, stream>>>(w1, w2, Wp1, Wp2);
  k_conv_gemm2<<<dim3(72, 1, 4), 256, 0, stream>>>(Wp1, Ybt2, b1, Y1t2, nullptr);
  k_conv_gemm2<<<dim3(72, 1, 4), 256, 0, stream>>>(Wp2, Y1t2, b2, nullptr, out);
}